// Round 12
// baseline (495.634 us; speedup 1.0000x reference)
//
#include <hip/hip_runtime.h>
#include <math.h>

#define N_U 30000
#define N_I 15000
#define N_TOT 45000
#define D 64
#define NNZ 480000
#define B 2048
#define INV_TEMP 5.0f
#define LOG_EPS -18.420680743952367f
#define NEG_SLOPE 0.2f
#define LAMBDA1 0.2f
#define LAMBDA2 1e-7f

// MFMA-lse config
#define NSP 256
#define RSP_U 118      // ceil(30000/256)
#define RSP_I 59       // ceil(15000/256)
#define PAD_U 30144    // >= 30000 + 127 (deepest in-flight prefetch row) 
#define PAD_I 15040
#define SCALE_LOG2 7.2134752044448170f  // INV_TEMP * log2(e)  (folded into Q)
#define LN2F 0.6931471805599453f

typedef __attribute__((ext_vector_type(8))) short short8;
typedef __attribute__((ext_vector_type(4))) float f32x4;

__device__ inline float wred(float v) {
#pragma unroll
  for (int o = 32; o > 0; o >>= 1) v += __shfl_down(v, o, 64);
  return v;
}

__device__ inline float leaky(float v) { return (v >= 0.f) ? v : NEG_SLOPE * v; }

__device__ inline void atomMaxF(float* a, float v) {
  if (v >= 0.f) atomicMax((int*)a, __float_as_int(v));
  else atomicMin((unsigned int*)a, __float_as_uint(v));
}

__device__ inline unsigned short f2bf(float x) {
  unsigned u = __float_as_uint(x);
  unsigned r = u + 0x7FFFu + ((u >> 16) & 1u);
  return (unsigned short)(r >> 16);
}
__device__ inline float bf2f(unsigned short h) {
  return __uint_as_float(((unsigned)h) << 16);
}

// ---------------- init ----------------
__global__ void k_init(const float* __restrict__ Eu0, const float* __restrict__ Ei0,
                       float* fU, float* fI, float* sEu, float* sEi,
                       float* sGu, float* sGi, int* deg, float* acc) {
  int t = blockIdx.x * 256 + threadIdx.x;
  if (t < 16) acc[t] = (t >= 8) ? -INFINITY : 0.f;   // 8..15: per-layer el-max slots
  if (t < N_I) deg[t] = 0;
  if (t < N_U * D) {
    int n = t >> 6, c = t & 63;
    float v = Eu0[t];
    fU[(size_t)n * 128 + c] = v;
    sEu[t] = v; sGu[t] = v;
  } else if (t < N_TOT * D) {
    int j = t - N_U * D;
    int n = j >> 6, c = j & 63;
    float v = Ei0[j];
    fI[(size_t)n * 128 + c] = v;
    sEi[j] = v; sGi[j] = v;
  }
}

// ---------------- CSR build over item side ----------------
__global__ void k_deg(const int* __restrict__ ii, int* deg) {
  int e = blockIdx.x * 256 + threadIdx.x;
  if (e < NNZ) atomicAdd(&deg[ii[e]], 1);
}

__global__ void k_scan(const int* __restrict__ deg, int* rowptr, int* cursor) {
  __shared__ int buf[1024];
  __shared__ int carry;
  int tid = threadIdx.x;
  if (tid == 0) carry = 0;
  __syncthreads();
  for (int base = 0; base < N_I; base += 1024) {
    int v = (base + tid < N_I) ? deg[base + tid] : 0;
    buf[tid] = v;
    __syncthreads();
    for (int o = 1; o < 1024; o <<= 1) {
      int x = (tid >= o) ? buf[tid - o] : 0;
      __syncthreads();
      buf[tid] += x;
      __syncthreads();
    }
    if (base + tid < N_I) {
      int excl = carry + buf[tid] - v;
      rowptr[base + tid] = excl;
      cursor[base + tid] = excl;
    }
    __syncthreads();
    if (tid == 1023) carry += buf[1023];
    __syncthreads();
  }
  if (tid == 0) rowptr[N_I] = carry;
}

__global__ void k_fill(const int* __restrict__ ii, const float* __restrict__ vals,
                       int* cursor, int* u_srt, float* v_srt) {
  int e = blockIdx.x * 256 + threadIdx.x;
  if (e < NNZ) {
    int pos = atomicAdd(&cursor[ii[e]], 1);
    u_srt[pos] = e >> 4;
    v_srt[pos] = vals[e];
  }
}

// ---------------- GAT: feat = E @ W into fused[64:128], el/er ----------------
__global__ void k_feat(float* __restrict__ fU, float* __restrict__ fI,
                       const float* __restrict__ W, const float* __restrict__ al,
                       const float* __restrict__ ar,
                       float* __restrict__ el, float* __restrict__ er) {
  __shared__ float Ws[64 * 64];
  __shared__ float hs[16][64];
  int tid = threadIdx.x;
  for (int t = tid; t < 1024; t += 256) ((float4*)Ws)[t] = ((const float4*)W)[t];
  int g = tid >> 6, c = tid & 63;
  int n0 = blockIdx.x * 16 + g * 4;
  float* rows[4];
#pragma unroll
  for (int j = 0; j < 4; j++) {
    int node = n0 + j;
    rows[j] = nullptr;
    if (node < N_TOT) {
      rows[j] = (node < N_U) ? (fU + (size_t)node * 128) : (fI + (size_t)(node - N_U) * 128);
      hs[g * 4 + j][c] = rows[j][c];
    }
  }
  __syncthreads();
  float a0 = 0.f, a1 = 0.f, a2 = 0.f, a3 = 0.f;
#pragma unroll 8
  for (int k = 0; k < 64; ++k) {
    float w = Ws[k * 64 + c];
    a0 = fmaf(hs[g * 4 + 0][k], w, a0);
    a1 = fmaf(hs[g * 4 + 1][k], w, a1);
    a2 = fmaf(hs[g * 4 + 2][k], w, a2);
    a3 = fmaf(hs[g * 4 + 3][k], w, a3);
  }
  float accs[4] = {a0, a1, a2, a3};
  float alc = al[c], arc = ar[c];
#pragma unroll
  for (int j = 0; j < 4; j++) {
    int node = n0 + j;
    if (node >= N_TOT) continue;
    rows[j][64 + c] = accs[j];
    float pl = accs[j] * alc;
    float pr = accs[j] * arc;
#pragma unroll
    for (int o = 8; o >= 1; o >>= 1) {
      pl += __shfl_down(pl, o, 16);
      pr += __shfl_down(pr, o, 16);
    }
    if ((c & 15) == 0) {
      el[node * 4 + (c >> 4)] = pl;
      er[node * 4 + (c >> 4)] = pr;
    }
  }
}

// ---------------- per-head global max of el ----------------
__global__ void k_elmax(const float* __restrict__ el, float* __restrict__ dst) {
  __shared__ float red[4][4];
  int tid = threadIdx.x;
  int lane = tid & 63, wv = tid >> 6;
  float mx = -INFINITY;
  for (int t = blockIdx.x * 256 + tid; t < N_TOT * 4; t += 64 * 256)
    mx = fmaxf(mx, el[t]);
#pragma unroll
  for (int o = 4; o < 64; o <<= 1) mx = fmaxf(mx, __shfl_xor(mx, o, 64));
  if (lane < 4) red[wv][lane] = mx;
  __syncthreads();
  if (tid < 4) {
    float m2 = fmaxf(fmaxf(red[0][tid], red[1][tid]), fmaxf(red[2][tid], red[3][tid]));
    atomMaxF(dst + tid, m2);
  }
}

// ---------------- fused user-side layer (chain-free); optionally emits split-bf16 + row norm ----------------
__global__ void k_user_layer(const float* __restrict__ fU_cur, const float* __restrict__ fI_cur,
                             const float* __restrict__ el, const float* __restrict__ er,
                             const float* __restrict__ vals, const int* __restrict__ ii,
                             const float* __restrict__ elmx,
                             float* __restrict__ fU_nxt, float* __restrict__ sEu,
                             float* __restrict__ sGu,
                             unsigned short* __restrict__ EH, unsigned short* __restrict__ EL,
                             float* __restrict__ normArr) {
  int t = blockIdx.x * 256 + threadIdx.x;
  int u = t >> 6, c = t & 63;
  if (u >= N_U) return;
  int h = c >> 4;
  float eru = er[u * 4 + h];
  float m = leaky(elmx[h] + eru);
  const float* selfrow = fU_cur + (size_t)u * 128;
  float aself = __expf(leaky(el[u * 4 + h] + eru) - m);

  int idx[16]; float vv[16];
#pragma unroll
  for (int k = 0; k < 16; k++) { idx[k] = ii[u * 16 + k]; vv[k] = vals[u * 16 + k]; }
  float av[16];
#pragma unroll
  for (int k = 0; k < 16; k++)
    av[k] = __expf(leaky(el[(idx[k] + N_U) * 4 + h] + eru) - m);

  float den = aself;
#pragma unroll
  for (int k = 0; k < 16; k++) den += av[k];

  float o0 = aself * selfrow[64 + c], o1 = 0.f;
  float z0 = 0.f, z1 = 0.f;
#pragma unroll
  for (int k = 0; k < 16; k += 2) {
    const float* rA = fI_cur + (size_t)idx[k] * 128;
    const float* rB = fI_cur + (size_t)idx[k + 1] * 128;
    float eA = rA[c], fA = rA[64 + c];
    float eB = rB[c], fB = rB[64 + c];
    z0 = fmaf(vv[k], eA, z0);
    z1 = fmaf(vv[k + 1], eB, z1);
    o0 = fmaf(av[k], fA, o0);
    o1 = fmaf(av[k + 1], fB, o1);
  }
  float o = (o0 + o1) / den;
  float g = (o > 0.f) ? o : expm1f(o);
  float e_new = selfrow[c] + z0 + z1;
  fU_nxt[(size_t)u * 128 + c] = e_new;
  size_t off = (size_t)u * D + c;
  float s_final = sEu[off] + e_new;
  sEu[off] = s_final;
  sGu[off] += g;
  if (EH) {  // final layer: emit split-bf16 row + row-norm^2 (wave == row, lane == col)
    unsigned short hi = f2bf(s_final);
    EH[off] = hi;
    EL[off] = f2bf(s_final - bf2f(hi));
    float n2 = wred(s_final * s_final);
    if (c == 0) normArr[u] = n2;
  }
}

// ---------------- fused item-side layer (chain-free, CSR); optional bf16 emit ----------------
__global__ void k_item_layer(const float* __restrict__ fU_cur, const float* __restrict__ fI_cur,
                             const float* __restrict__ el, const float* __restrict__ er,
                             const int* __restrict__ rowptr, const int* __restrict__ u_srt,
                             const float* __restrict__ v_srt,
                             const float* __restrict__ elmx,
                             float* __restrict__ fI_nxt, float* __restrict__ sEi,
                             float* __restrict__ sGi,
                             unsigned short* __restrict__ EH, unsigned short* __restrict__ EL,
                             float* __restrict__ normArr) {
  int t = blockIdx.x * 256 + threadIdx.x;
  int i = t >> 6, c = t & 63;
  if (i >= N_I) return;
  int h = c >> 4;
  int node = N_U + i;
  float eri = er[node * 4 + h];
  float m = leaky(elmx[h] + eri);
  const float* selfrow = fI_cur + (size_t)i * 128;
  float aself = __expf(leaky(el[node * 4 + h] + eri) - m);
  float den0 = aself, den1 = 0.f;
  float o0 = aself * selfrow[64 + c], o1 = 0.f;
  float z0 = 0.f, z1 = 0.f;
  int r0 = rowptr[i], r1 = rowptr[i + 1];
  int r = r0;
  for (; r + 3 < r1; r += 4) {
    int u0 = u_srt[r], u1 = u_srt[r + 1], u2 = u_srt[r + 2], u3 = u_srt[r + 3];
    float v0 = v_srt[r], v1 = v_srt[r + 1], v2 = v_srt[r + 2], v3 = v_srt[r + 3];
    float a0 = __expf(leaky(el[u0 * 4 + h] + eri) - m);
    float a1 = __expf(leaky(el[u1 * 4 + h] + eri) - m);
    float a2 = __expf(leaky(el[u2 * 4 + h] + eri) - m);
    float a3 = __expf(leaky(el[u3 * 4 + h] + eri) - m);
    const float* R0 = fU_cur + (size_t)u0 * 128;
    const float* R1 = fU_cur + (size_t)u1 * 128;
    const float* R2 = fU_cur + (size_t)u2 * 128;
    const float* R3 = fU_cur + (size_t)u3 * 128;
    float e0 = R0[c], f0 = R0[64 + c];
    float e1 = R1[c], f1 = R1[64 + c];
    float e2 = R2[c], f2 = R2[64 + c];
    float e3 = R3[c], f3 = R3[64 + c];
    z0 = fmaf(v0, e0, z0); z1 = fmaf(v1, e1, z1);
    z0 = fmaf(v2, e2, z0); z1 = fmaf(v3, e3, z1);
    den0 += a0 + a2; den1 += a1 + a3;
    o0 = fmaf(a0, f0, o0); o1 = fmaf(a1, f1, o1);
    o0 = fmaf(a2, f2, o0); o1 = fmaf(a3, f3, o1);
  }
  for (; r < r1; r++) {
    int u0 = u_srt[r];
    float v0 = v_srt[r];
    float a0 = __expf(leaky(el[u0 * 4 + h] + eri) - m);
    const float* R0 = fU_cur + (size_t)u0 * 128;
    float e0 = R0[c], f0 = R0[64 + c];
    z0 = fmaf(v0, e0, z0);
    den0 += a0;
    o0 = fmaf(a0, f0, o0);
  }
  float o = (o0 + o1) / (den0 + den1);
  float g = (o > 0.f) ? o : expm1f(o);
  float e_new = selfrow[c] + z0 + z1;
  fI_nxt[(size_t)i * 128 + c] = e_new;
  size_t off = (size_t)i * D + c;
  float s_final = sEi[off] + e_new;
  sEi[off] = s_final;
  sGi[off] += g;
  if (EH) {
    unsigned short hi = f2bf(s_final);
    EH[off] = hi;
    EL[off] = f2bf(s_final - bf2f(hi));
    float n2 = wred(s_final * s_final);
    if (c == 0) normArr[i] = n2;
  }
}

// ---------------- max row-norm reduce (both sides) ----------------
__global__ void k_norm_max(const float* __restrict__ nU, const float* __restrict__ nI,
                           float* __restrict__ acc) {
  __shared__ float red[4][2];
  int tid = threadIdx.x;
  int lane = tid & 63, wv = tid >> 6;
  float mu = 0.f, mi = 0.f;
  for (int t = blockIdx.x * 256 + tid; t < N_U; t += 64 * 256) mu = fmaxf(mu, nU[t]);
  for (int t = blockIdx.x * 256 + tid; t < N_I; t += 64 * 256) mi = fmaxf(mi, nI[t]);
#pragma unroll
  for (int o = 32; o > 0; o >>= 1) {
    mu = fmaxf(mu, __shfl_down(mu, o, 64));
    mi = fmaxf(mi, __shfl_down(mi, o, 64));
  }
  if (lane == 0) { red[wv][0] = mu; red[wv][1] = mi; }
  __syncthreads();
  if (tid == 0) {
    float a = fmaxf(fmaxf(red[0][0], red[1][0]), fmaxf(red[2][0], red[3][0]));
    float b = fmaxf(fmaxf(red[0][1], red[1][1]), fmaxf(red[2][1], red[3][1]));
    atomMaxF(acc + 6, a);
    atomMaxF(acc + 7, b);
  }
}

// ---------------- gathered queries: pre-scaled split-bf16 + Cauchy-Schwarz offset M0 ----------------
// n2 is norm^2 of the ALREADY-SCALED query; acc[6/7] are UNSCALED E norms.
__global__ void k_cvt_q(const float* __restrict__ sGu, const float* __restrict__ sGi,
                        const int* __restrict__ uids, const int* __restrict__ iids,
                        unsigned short* __restrict__ QuH, unsigned short* __restrict__ QuL,
                        unsigned short* __restrict__ QiH, unsigned short* __restrict__ QiL,
                        const float* __restrict__ acc,
                        float* __restrict__ M0u, float* __restrict__ M0i) {
  int lane = threadIdx.x & 63, wv = threadIdx.x >> 6;
  int row = blockIdx.x * 4 + wv;
  int side = row >> 11;
  int b = row & (B - 1);
  int id = side ? iids[b] : uids[b];
  float x = (side ? sGi : sGu)[(size_t)id * 64 + lane] * SCALE_LOG2;
  unsigned short hi = f2bf(x);
  unsigned short lo = f2bf(x - bf2f(hi));
  if (side) { QiH[(size_t)b * 64 + lane] = hi; QiL[(size_t)b * 64 + lane] = lo; }
  else      { QuH[(size_t)b * 64 + lane] = hi; QuL[(size_t)b * 64 + lane] = lo; }
  float n2 = wred(x * x);
  if (lane == 0) {
    float en2 = side ? acc[7] : acc[6];
    float M0 = sqrtf(n2) * sqrtf(en2) * 1.01f + 1.0f;
    (side ? M0i : M0u)[b] = M0;
  }
}

// ---------------- MFMA logsumexp: fixed offset, register double-buffered ----------------
// Grid (B/256, NSP): 2048 blocks (8/CU queued) for occupancy; per-block work halved.
// Pad rows are loaded (in-bounds) but masked — never contribute.
__global__ __launch_bounds__(256) void k_lse_mfma(
    const unsigned short* __restrict__ Qhi, const unsigned short* __restrict__ Qlo,
    const unsigned short* __restrict__ Ehi, const unsigned short* __restrict__ Elo,
    const float* __restrict__ M0arr,
    int n_rows, int rows_per_split,
    float* __restrict__ part_s) {
  int tid = threadIdx.x;
  int wave = tid >> 6, lane = tid & 63;
  int l15 = lane & 15, quad = lane >> 4;
  int qt0 = blockIdx.x * 256 + wave * 64;
  int split = blockIdx.y;
  int row0 = split * rows_per_split;
  int row_end = min(row0 + rows_per_split, n_rows);
  int rows = row_end - row0; if (rows < 0) rows = 0;
  int total = (rows + 15) >> 4;
  int ntail = rows & 15;

  float ss[4][4];
#pragma unroll
  for (int t = 0; t < 4; t++)
#pragma unroll
    for (int g = 0; g < 4; g++) ss[t][g] = 0.f;

  if (total > 0) {
    short8 ah[4][2], al[4][2];
#pragma unroll
    for (int t = 0; t < 4; t++)
#pragma unroll
      for (int c = 0; c < 2; c++) {
        size_t idx = (size_t)(qt0 + t * 16 + l15) * 64 + c * 32 + quad * 8;
        ah[t][c] = *(const short8*)(Qhi + idx);
        al[t][c] = *(const short8*)(Qlo + idx);
      }

    f32x4 cinit[4];
#pragma unroll
    for (int t = 0; t < 4; t++)
#pragma unroll
      for (int g = 0; g < 4; g++)
        cinit[t][g] = -M0arr[qt0 + t * 16 + quad * 4 + g];

    const unsigned short* ph = Ehi + (size_t)(row0 + l15) * 64 + quad * 8;
    const unsigned short* pl = Elo + (size_t)(row0 + l15) * 64 + quad * 8;

    short8 cb0 = *(const short8*)(ph);
    short8 cb1 = *(const short8*)(ph + 32);
    short8 cb2 = *(const short8*)(pl);
    short8 cb3 = *(const short8*)(pl + 32);
    ph += 1024; pl += 1024;

    for (int it = 0; it < total - 1; it++) {
      short8 nb0 = *(const short8*)(ph);
      short8 nb1 = *(const short8*)(ph + 32);
      short8 nb2 = *(const short8*)(pl);
      short8 nb3 = *(const short8*)(pl + 32);
      ph += 1024; pl += 1024;
#pragma unroll
      for (int t = 0; t < 4; t++) {
        f32x4 acc = cinit[t];
        acc = __builtin_amdgcn_mfma_f32_16x16x32_bf16(ah[t][0], cb0, acc, 0, 0, 0);
        acc = __builtin_amdgcn_mfma_f32_16x16x32_bf16(ah[t][1], cb1, acc, 0, 0, 0);
        acc = __builtin_amdgcn_mfma_f32_16x16x32_bf16(al[t][0], cb0, acc, 0, 0, 0);
        acc = __builtin_amdgcn_mfma_f32_16x16x32_bf16(al[t][1], cb1, acc, 0, 0, 0);
        acc = __builtin_amdgcn_mfma_f32_16x16x32_bf16(ah[t][0], cb2, acc, 0, 0, 0);
        acc = __builtin_amdgcn_mfma_f32_16x16x32_bf16(ah[t][1], cb3, acc, 0, 0, 0);
#pragma unroll
        for (int g = 0; g < 4; g++)
          ss[t][g] += exp2f(acc[g]);
      }
      cb0 = nb0; cb1 = nb1; cb2 = nb2; cb3 = nb3;
    }
    {  // last tile (masked iff ntail != 0)
      bool valid = (ntail == 0) || (l15 < ntail);
#pragma unroll
      for (int t = 0; t < 4; t++) {
        f32x4 acc = cinit[t];
        acc = __builtin_amdgcn_mfma_f32_16x16x32_bf16(ah[t][0], cb0, acc, 0, 0, 0);
        acc = __builtin_amdgcn_mfma_f32_16x16x32_bf16(ah[t][1], cb1, acc, 0, 0, 0);
        acc = __builtin_amdgcn_mfma_f32_16x16x32_bf16(al[t][0], cb0, acc, 0, 0, 0);
        acc = __builtin_amdgcn_mfma_f32_16x16x32_bf16(al[t][1], cb1, acc, 0, 0, 0);
        acc = __builtin_amdgcn_mfma_f32_16x16x32_bf16(ah[t][0], cb2, acc, 0, 0, 0);
        acc = __builtin_amdgcn_mfma_f32_16x16x32_bf16(ah[t][1], cb3, acc, 0, 0, 0);
#pragma unroll
        for (int g = 0; g < 4; g++) {
          float e = exp2f(acc[g]);
          ss[t][g] += valid ? e : 0.f;
        }
      }
    }
  }

#pragma unroll
  for (int off = 1; off < 16; off <<= 1) {
#pragma unroll
    for (int t = 0; t < 4; t++)
#pragma unroll
      for (int g = 0; g < 4; g++)
        ss[t][g] += __shfl_xor(ss[t][g], off, 64);
  }

  if (l15 == 0) {
#pragma unroll
    for (int t = 0; t < 4; t++)
#pragma unroll
      for (int g = 0; g < 4; g++) {
        int q = qt0 + t * 16 + quad * 4 + g;
        part_s[(size_t)split * B + q] = ss[t][g];
      }
  }
}

// ---------------- L2 regularization reduce ----------------
__global__ void k_reg(const float* __restrict__ Eu0, const float* __restrict__ Ei0, float* acc) {
  __shared__ float red[4];
  int tid = threadIdx.x;
  float s = 0.f;
  const float4* A = (const float4*)Eu0;
  const float4* Bp = (const float4*)Ei0;
  const int nA = N_U * 16, nTot = N_TOT * 16;
  for (int t = blockIdx.x * 256 + tid; t < nTot; t += 256 * 256) {
    float4 v = (t < nA) ? A[t] : Bp[t - nA];
    s += v.x * v.x + v.y * v.y + v.z * v.z + v.w * v.w;
  }
  s = wred(s);
  if ((tid & 63) == 0) red[tid >> 6] = s;
  __syncthreads();
  if (tid == 0) unsafeAtomicAdd(acc + 5, red[0] + red[1] + red[2] + red[3]);
}

// ---------------- per-sample losses ----------------
__global__ void k_small(const float* __restrict__ sEu, const float* __restrict__ sEi,
                        const float* __restrict__ sGu, const float* __restrict__ sGi,
                        const int* __restrict__ uids, const int* __restrict__ iids,
                        const int* __restrict__ pos, const int* __restrict__ neg,
                        const float* __restrict__ psU, const float* __restrict__ psI,
                        const float* __restrict__ M0u, const float* __restrict__ M0i,
                        float* acc) {
  int b = blockIdx.x * 256 + threadIdx.x;
  float du = 0.f, di = 0.f, nu = 0.f, ni = 0.f, bpr = 0.f;
  if (b < B) {
    float su = 0.f, si = 0.f;
    for (int s2 = 0; s2 < NSP; s2++) su += psU[(size_t)s2 * B + b];
    for (int s2 = 0; s2 < NSP; s2++) si += psI[(size_t)s2 * B + b];
    float lseu = M0u[b] * LN2F + logf(su);
    float lsei = M0i[b] * LN2F + logf(si);
    nu = fmaxf(lseu, LOG_EPS) + log1pf(expf(-fabsf(lseu - LOG_EPS)));
    ni = fmaxf(lsei, LOG_EPS) + log1pf(expf(-fabsf(lsei - LOG_EPS)));

    int u = uids[b], it = iids[b], p = pos[b], ng = neg[b];
    const float4* gu = (const float4*)(sGu + (size_t)u * D);
    const float4* eu = (const float4*)(sEu + (size_t)u * D);
    const float4* gi = (const float4*)(sGi + (size_t)it * D);
    const float4* ei = (const float4*)(sEi + (size_t)it * D);
    const float4* ep = (const float4*)(sEi + (size_t)p * D);
    const float4* en = (const float4*)(sEi + (size_t)ng * D);
    float diff = 0.f;
#pragma unroll
    for (int k = 0; k < 16; k++) {
      float4 a = gu[k], b4 = eu[k];
      du += a.x * b4.x + a.y * b4.y + a.z * b4.z + a.w * b4.w;
      float4 c = gi[k], d4 = ei[k];
      di += c.x * d4.x + c.y * d4.y + c.z * d4.z + c.w * d4.w;
      float4 e = ep[k], f = en[k];
      diff += b4.x * (e.x - f.x) + b4.y * (e.y - f.y) + b4.z * (e.z - f.z) + b4.w * (e.w - f.w);
    }
    bpr = (diff > 0.f) ? log1pf(expf(-diff)) : (-diff + log1pf(expf(diff)));
  }
  du = wred(du); di = wred(di); nu = wred(nu); ni = wred(ni); bpr = wred(bpr);
  if ((threadIdx.x & 63) == 0) {
    unsafeAtomicAdd(acc + 0, du);
    unsafeAtomicAdd(acc + 1, di);
    unsafeAtomicAdd(acc + 2, nu);
    unsafeAtomicAdd(acc + 3, ni);
    unsafeAtomicAdd(acc + 4, bpr);
  }
}

// ---------------- finalize ----------------
__global__ void k_final(const float* __restrict__ acc, float* __restrict__ out) {
  float pos_score = (acc[0] + acc[1]) * (INV_TEMP / (float)B);
  float neg_score = (acc[2] + acc[3]) / (float)B;
  float loss_s = neg_score - pos_score;
  float loss_r = acc[4] / (float)B;
  float reg = LAMBDA2 * acc[5];
  out[0] = loss_r + LAMBDA1 * loss_s + reg;
  out[1] = loss_r;
  out[2] = LAMBDA1 * loss_s;
}

extern "C" void kernel_launch(void* const* d_in, const int* in_sizes, int n_in,
                              void* d_out, int out_size, void* d_ws, size_t ws_size,
                              hipStream_t stream) {
  const float* Eu0  = (const float*)d_in[0];
  const float* Ei0  = (const float*)d_in[1];
  const float* vals = (const float*)d_in[2];
  const float* W    = (const float*)d_in[3];
  const float* al   = (const float*)d_in[4];
  const float* ar   = (const float*)d_in[5];
  const int* ii     = (const int*)d_in[7];
  const int* uids   = (const int*)d_in[10];
  const int* iids   = (const int*)d_in[11];
  const int* pos    = (const int*)d_in[12];
  const int* neg    = (const int*)d_in[13];
  float* out = (float*)d_out;

  char* base = (char*)d_ws;
  size_t off = 0;
  auto alloc = [&](size_t bytes) -> void* {
    void* p = base + off;
    off = (off + bytes + 255) & ~(size_t)255;
    return p;
  };
  float* fU_a = (float*)alloc((size_t)N_U * 128 * 4);
  float* fU_b = (float*)alloc((size_t)N_U * 128 * 4);
  float* fI_a = (float*)alloc((size_t)N_I * 128 * 4);
  float* fI_b = (float*)alloc((size_t)N_I * 128 * 4);
  float* sEu  = (float*)alloc((size_t)N_U * D * 4);
  float* sEi  = (float*)alloc((size_t)N_I * D * 4);
  float* sGu  = (float*)alloc((size_t)N_U * D * 4);
  float* sGi  = (float*)alloc((size_t)N_I * D * 4);
  float* el   = (float*)alloc((size_t)N_TOT * 4 * 4);
  float* er   = (float*)alloc((size_t)N_TOT * 4 * 4);
  float* psU  = (float*)alloc((size_t)B * NSP * 4);
  float* psI  = (float*)alloc((size_t)B * NSP * 4);
  float* M0u  = (float*)alloc((size_t)B * 4);
  float* M0i  = (float*)alloc((size_t)B * 4);
  float* normU= (float*)alloc((size_t)N_U * 4);
  float* normI= (float*)alloc((size_t)N_I * 4);
  float* acc  = (float*)alloc(16 * 4);
  int* deg    = (int*)alloc((size_t)N_I * 4);
  int* cursor = (int*)alloc((size_t)N_I * 4);
  int* rowptr = (int*)alloc((size_t)(N_I + 1) * 4);
  int* u_srt  = (int*)alloc((size_t)NNZ * 4);
  float* v_srt= (float*)alloc((size_t)NNZ * 4);
  unsigned short* EuH = (unsigned short*)alloc((size_t)PAD_U * 64 * 2);
  unsigned short* EuL = (unsigned short*)alloc((size_t)PAD_U * 64 * 2);
  unsigned short* EiH = (unsigned short*)alloc((size_t)PAD_I * 64 * 2);
  unsigned short* EiL = (unsigned short*)alloc((size_t)PAD_I * 64 * 2);
  unsigned short* QuH = (unsigned short*)alloc((size_t)B * 64 * 2);
  unsigned short* QuL = (unsigned short*)alloc((size_t)B * 64 * 2);
  unsigned short* QiH = (unsigned short*)alloc((size_t)B * 64 * 2);
  unsigned short* QiL = (unsigned short*)alloc((size_t)B * 64 * 2);

  k_init<<<(N_TOT * D + 255) / 256, 256, 0, stream>>>(Eu0, Ei0, fU_a, fI_a, sEu, sEi, sGu, sGi,
                                                      deg, acc);
  k_deg<<<(NNZ + 255) / 256, 256, 0, stream>>>(ii, deg);
  k_scan<<<1, 1024, 0, stream>>>(deg, rowptr, cursor);
  k_fill<<<(NNZ + 255) / 256, 256, 0, stream>>>(ii, vals, cursor, u_srt, v_srt);

  float* cu = fU_a; float* ci = fI_a;
  float* nu = fU_b; float* ni = fI_b;
  for (int l = 0; l < 2; ++l) {
    float* elmx = acc + 8 + 4 * l;
    bool last = (l == 1);
    k_feat<<<(N_TOT + 15) / 16, 256, 0, stream>>>(cu, ci, W, al, ar, el, er);
    k_elmax<<<64, 256, 0, stream>>>(el, elmx);
    k_user_layer<<<(N_U * D) / 256, 256, 0, stream>>>(cu, ci, el, er, vals, ii, elmx, nu, sEu, sGu,
                                                      last ? EuH : nullptr, last ? EuL : nullptr,
                                                      normU);
    k_item_layer<<<(N_I * D) / 256, 256, 0, stream>>>(cu, ci, el, er, rowptr, u_srt, v_srt, elmx,
                                                      ni, sEi, sGi,
                                                      last ? EiH : nullptr, last ? EiL : nullptr,
                                                      normI);
    float* t1 = cu; cu = nu; nu = t1;
    float* t2 = ci; ci = ni; ni = t2;
  }

  k_norm_max<<<64, 256, 0, stream>>>(normU, normI, acc);
  k_cvt_q<<<(2 * B) / 4, 256, 0, stream>>>(sGu, sGi, uids, iids, QuH, QuL, QiH, QiL, acc, M0u, M0i);
  k_lse_mfma<<<dim3(B / 256, NSP), 256, 0, stream>>>(QuH, QuL, EuH, EuL, M0u, N_U, RSP_U, psU);
  k_lse_mfma<<<dim3(B / 256, NSP), 256, 0, stream>>>(QiH, QiL, EiH, EiL, M0i, N_I, RSP_I, psI);
  k_reg<<<256, 256, 0, stream>>>(Eu0, Ei0, acc);
  k_small<<<B / 256, 256, 0, stream>>>(sEu, sEi, sGu, sGi, uids, iids, pos, neg,
                                       psU, psI, M0u, M0i, acc);
  k_final<<<1, 1, 0, stream>>>(acc, out);
}

// Round 13
// 464.316 us; speedup vs baseline: 1.0675x; 1.0675x over previous
//
#include <hip/hip_runtime.h>
#include <math.h>

#define N_U 30000
#define N_I 15000
#define N_TOT 45000
#define D 64
#define NNZ 480000
#define B 2048
#define INV_TEMP 5.0f
#define LOG_EPS -18.420680743952367f
#define NEG_SLOPE 0.2f
#define LAMBDA1 0.2f
#define LAMBDA2 1e-7f

// MFMA-lse config
#define NSP 128
#define RSP_U 235      // ceil(30000/128)
#define RSP_I 118      // ceil(15000/128)
#define PAD_U 30016
#define PAD_I 15040
#define SCALE_LOG2 7.2134752044448170f  // INV_TEMP * log2(e)  (folded into Q)
#define LN2F 0.6931471805599453f

typedef __attribute__((ext_vector_type(8))) short short8;
typedef __attribute__((ext_vector_type(4))) float f32x4;

__device__ inline float wred(float v) {
#pragma unroll
  for (int o = 32; o > 0; o >>= 1) v += __shfl_down(v, o, 64);
  return v;
}

__device__ inline float leaky(float v) { return (v >= 0.f) ? v : NEG_SLOPE * v; }

__device__ inline void atomMaxF(float* a, float v) {
  if (v >= 0.f) atomicMax((int*)a, __float_as_int(v));
  else atomicMin((unsigned int*)a, __float_as_uint(v));
}

__device__ inline unsigned short f2bf(float x) {
  unsigned u = __float_as_uint(x);
  unsigned r = u + 0x7FFFu + ((u >> 16) & 1u);
  return (unsigned short)(r >> 16);
}
__device__ inline float bf2f(unsigned short h) {
  return __uint_as_float(((unsigned)h) << 16);
}

// ---------------- init ----------------
__global__ void k_init(const float* __restrict__ Eu0, const float* __restrict__ Ei0,
                       float* fU, float* fI, float* sEu, float* sEi,
                       float* sGu, float* sGi, int* deg, float* acc) {
  int t = blockIdx.x * 256 + threadIdx.x;
  if (t < 16) acc[t] = (t >= 8) ? -INFINITY : 0.f;
  if (t < N_I) deg[t] = 0;
  if (t < N_U * D) {
    int n = t >> 6, c = t & 63;
    float v = Eu0[t];
    fU[(size_t)n * 128 + c] = v;
    sEu[t] = v; sGu[t] = v;
  } else if (t < N_TOT * D) {
    int j = t - N_U * D;
    int n = j >> 6, c = j & 63;
    float v = Ei0[j];
    fI[(size_t)n * 128 + c] = v;
    sEi[j] = v; sGi[j] = v;
  }
}

// ---------------- CSR build over item side ----------------
__global__ void k_deg(const int* __restrict__ ii, int* deg) {
  int e = blockIdx.x * 256 + threadIdx.x;
  if (e < NNZ) atomicAdd(&deg[ii[e]], 1);
}

__global__ void k_scan(const int* __restrict__ deg, int* rowptr, int* cursor) {
  __shared__ int buf[1024];
  __shared__ int carry;
  int tid = threadIdx.x;
  if (tid == 0) carry = 0;
  __syncthreads();
  for (int base = 0; base < N_I; base += 1024) {
    int v = (base + tid < N_I) ? deg[base + tid] : 0;
    buf[tid] = v;
    __syncthreads();
    for (int o = 1; o < 1024; o <<= 1) {
      int x = (tid >= o) ? buf[tid - o] : 0;
      __syncthreads();
      buf[tid] += x;
      __syncthreads();
    }
    if (base + tid < N_I) {
      int excl = carry + buf[tid] - v;
      rowptr[base + tid] = excl;
      cursor[base + tid] = excl;
    }
    __syncthreads();
    if (tid == 1023) carry += buf[1023];
    __syncthreads();
  }
  if (tid == 0) rowptr[N_I] = carry;
}

__global__ void k_fill(const int* __restrict__ ii, const float* __restrict__ vals,
                       int* cursor, int* u_srt, float* v_srt) {
  int e = blockIdx.x * 256 + threadIdx.x;
  if (e < NNZ) {
    int pos = atomicAdd(&cursor[ii[e]], 1);
    u_srt[pos] = e >> 4;
    v_srt[pos] = vals[e];
  }
}

// ---------------- GAT: feat = E @ W into fused[64:128], el/er ----------------
__global__ void k_feat(float* __restrict__ fU, float* __restrict__ fI,
                       const float* __restrict__ W, const float* __restrict__ al,
                       const float* __restrict__ ar,
                       float* __restrict__ el, float* __restrict__ er) {
  __shared__ float Ws[64 * 64];
  __shared__ float hs[16][64];
  int tid = threadIdx.x;
  for (int t = tid; t < 1024; t += 256) ((float4*)Ws)[t] = ((const float4*)W)[t];
  int g = tid >> 6, c = tid & 63;
  int n0 = blockIdx.x * 16 + g * 4;
  float* rows[4];
#pragma unroll
  for (int j = 0; j < 4; j++) {
    int node = n0 + j;
    rows[j] = nullptr;
    if (node < N_TOT) {
      rows[j] = (node < N_U) ? (fU + (size_t)node * 128) : (fI + (size_t)(node - N_U) * 128);
      hs[g * 4 + j][c] = rows[j][c];
    }
  }
  __syncthreads();
  float a0 = 0.f, a1 = 0.f, a2 = 0.f, a3 = 0.f;
#pragma unroll 8
  for (int k = 0; k < 64; ++k) {
    float w = Ws[k * 64 + c];
    a0 = fmaf(hs[g * 4 + 0][k], w, a0);
    a1 = fmaf(hs[g * 4 + 1][k], w, a1);
    a2 = fmaf(hs[g * 4 + 2][k], w, a2);
    a3 = fmaf(hs[g * 4 + 3][k], w, a3);
  }
  float accs[4] = {a0, a1, a2, a3};
  float alc = al[c], arc = ar[c];
#pragma unroll
  for (int j = 0; j < 4; j++) {
    int node = n0 + j;
    if (node >= N_TOT) continue;
    rows[j][64 + c] = accs[j];
    float pl = accs[j] * alc;
    float pr = accs[j] * arc;
#pragma unroll
    for (int o = 8; o >= 1; o >>= 1) {
      pl += __shfl_down(pl, o, 16);
      pr += __shfl_down(pr, o, 16);
    }
    if ((c & 15) == 0) {
      el[node * 4 + (c >> 4)] = pl;
      er[node * 4 + (c >> 4)] = pr;
    }
  }
}

// ---------------- per-head global max of el ----------------
__global__ void k_elmax(const float* __restrict__ el, float* __restrict__ dst) {
  __shared__ float red[4][4];
  int tid = threadIdx.x;
  int lane = tid & 63, wv = tid >> 6;
  float mx = -INFINITY;
  for (int t = blockIdx.x * 256 + tid; t < N_TOT * 4; t += 64 * 256)
    mx = fmaxf(mx, el[t]);
#pragma unroll
  for (int o = 4; o < 64; o <<= 1) mx = fmaxf(mx, __shfl_xor(mx, o, 64));
  if (lane < 4) red[wv][lane] = mx;
  __syncthreads();
  if (tid < 4) {
    float m2 = fmaxf(fmaxf(red[0][tid], red[1][tid]), fmaxf(red[2][tid], red[3][tid]));
    atomMaxF(dst + tid, m2);
  }
}

// ---------------- fused user-side layer (chain-free); optionally emits split-bf16 + row norm ----------------
__global__ void k_user_layer(const float* __restrict__ fU_cur, const float* __restrict__ fI_cur,
                             const float* __restrict__ el, const float* __restrict__ er,
                             const float* __restrict__ vals, const int* __restrict__ ii,
                             const float* __restrict__ elmx,
                             float* __restrict__ fU_nxt, float* __restrict__ sEu,
                             float* __restrict__ sGu,
                             unsigned short* __restrict__ EH, unsigned short* __restrict__ EL,
                             float* __restrict__ normArr) {
  int t = blockIdx.x * 256 + threadIdx.x;
  int u = t >> 6, c = t & 63;
  if (u >= N_U) return;
  int h = c >> 4;
  float eru = er[u * 4 + h];
  float m = leaky(elmx[h] + eru);
  const float* selfrow = fU_cur + (size_t)u * 128;
  float aself = __expf(leaky(el[u * 4 + h] + eru) - m);

  int idx[16]; float vv[16];
#pragma unroll
  for (int k = 0; k < 16; k++) { idx[k] = ii[u * 16 + k]; vv[k] = vals[u * 16 + k]; }
  float av[16];
#pragma unroll
  for (int k = 0; k < 16; k++)
    av[k] = __expf(leaky(el[(idx[k] + N_U) * 4 + h] + eru) - m);

  float den = aself;
#pragma unroll
  for (int k = 0; k < 16; k++) den += av[k];

  float o0 = aself * selfrow[64 + c], o1 = 0.f;
  float z0 = 0.f, z1 = 0.f;
#pragma unroll
  for (int k = 0; k < 16; k += 2) {
    const float* rA = fI_cur + (size_t)idx[k] * 128;
    const float* rB = fI_cur + (size_t)idx[k + 1] * 128;
    float eA = rA[c], fA = rA[64 + c];
    float eB = rB[c], fB = rB[64 + c];
    z0 = fmaf(vv[k], eA, z0);
    z1 = fmaf(vv[k + 1], eB, z1);
    o0 = fmaf(av[k], fA, o0);
    o1 = fmaf(av[k + 1], fB, o1);
  }
  float o = (o0 + o1) / den;
  float g = (o > 0.f) ? o : expm1f(o);
  float e_new = selfrow[c] + z0 + z1;
  fU_nxt[(size_t)u * 128 + c] = e_new;
  size_t off = (size_t)u * D + c;
  float s_final = sEu[off] + e_new;
  sEu[off] = s_final;
  sGu[off] += g;
  if (EH) {
    unsigned short hi = f2bf(s_final);
    EH[off] = hi;
    EL[off] = f2bf(s_final - bf2f(hi));
    float n2 = wred(s_final * s_final);
    if (c == 0) normArr[u] = n2;
  }
}

// ---------------- fused item-side layer (chain-free, CSR); optional bf16 emit ----------------
__global__ void k_item_layer(const float* __restrict__ fU_cur, const float* __restrict__ fI_cur,
                             const float* __restrict__ el, const float* __restrict__ er,
                             const int* __restrict__ rowptr, const int* __restrict__ u_srt,
                             const float* __restrict__ v_srt,
                             const float* __restrict__ elmx,
                             float* __restrict__ fI_nxt, float* __restrict__ sEi,
                             float* __restrict__ sGi,
                             unsigned short* __restrict__ EH, unsigned short* __restrict__ EL,
                             float* __restrict__ normArr) {
  int t = blockIdx.x * 256 + threadIdx.x;
  int i = t >> 6, c = t & 63;
  if (i >= N_I) return;
  int h = c >> 4;
  int node = N_U + i;
  float eri = er[node * 4 + h];
  float m = leaky(elmx[h] + eri);
  const float* selfrow = fI_cur + (size_t)i * 128;
  float aself = __expf(leaky(el[node * 4 + h] + eri) - m);
  float den0 = aself, den1 = 0.f;
  float o0 = aself * selfrow[64 + c], o1 = 0.f;
  float z0 = 0.f, z1 = 0.f;
  int r0 = rowptr[i], r1 = rowptr[i + 1];
  int r = r0;
  for (; r + 3 < r1; r += 4) {
    int u0 = u_srt[r], u1 = u_srt[r + 1], u2 = u_srt[r + 2], u3 = u_srt[r + 3];
    float v0 = v_srt[r], v1 = v_srt[r + 1], v2 = v_srt[r + 2], v3 = v_srt[r + 3];
    float a0 = __expf(leaky(el[u0 * 4 + h] + eri) - m);
    float a1 = __expf(leaky(el[u1 * 4 + h] + eri) - m);
    float a2 = __expf(leaky(el[u2 * 4 + h] + eri) - m);
    float a3 = __expf(leaky(el[u3 * 4 + h] + eri) - m);
    const float* R0 = fU_cur + (size_t)u0 * 128;
    const float* R1 = fU_cur + (size_t)u1 * 128;
    const float* R2 = fU_cur + (size_t)u2 * 128;
    const float* R3 = fU_cur + (size_t)u3 * 128;
    float e0 = R0[c], f0 = R0[64 + c];
    float e1 = R1[c], f1 = R1[64 + c];
    float e2 = R2[c], f2 = R2[64 + c];
    float e3 = R3[c], f3 = R3[64 + c];
    z0 = fmaf(v0, e0, z0); z1 = fmaf(v1, e1, z1);
    z0 = fmaf(v2, e2, z0); z1 = fmaf(v3, e3, z1);
    den0 += a0 + a2; den1 += a1 + a3;
    o0 = fmaf(a0, f0, o0); o1 = fmaf(a1, f1, o1);
    o0 = fmaf(a2, f2, o0); o1 = fmaf(a3, f3, o1);
  }
  for (; r < r1; r++) {
    int u0 = u_srt[r];
    float v0 = v_srt[r];
    float a0 = __expf(leaky(el[u0 * 4 + h] + eri) - m);
    const float* R0 = fU_cur + (size_t)u0 * 128;
    float e0 = R0[c], f0 = R0[64 + c];
    z0 = fmaf(v0, e0, z0);
    den0 += a0;
    o0 = fmaf(a0, f0, o0);
  }
  float o = (o0 + o1) / (den0 + den1);
  float g = (o > 0.f) ? o : expm1f(o);
  float e_new = selfrow[c] + z0 + z1;
  fI_nxt[(size_t)i * 128 + c] = e_new;
  size_t off = (size_t)i * D + c;
  float s_final = sEi[off] + e_new;
  sEi[off] = s_final;
  sGi[off] += g;
  if (EH) {
    unsigned short hi = f2bf(s_final);
    EH[off] = hi;
    EL[off] = f2bf(s_final - bf2f(hi));
    float n2 = wred(s_final * s_final);
    if (c == 0) normArr[i] = n2;
  }
}

// ---------------- max row-norm reduce (both sides) ----------------
__global__ void k_norm_max(const float* __restrict__ nU, const float* __restrict__ nI,
                           float* __restrict__ acc) {
  __shared__ float red[4][2];
  int tid = threadIdx.x;
  int lane = tid & 63, wv = tid >> 6;
  float mu = 0.f, mi = 0.f;
  for (int t = blockIdx.x * 256 + tid; t < N_U; t += 64 * 256) mu = fmaxf(mu, nU[t]);
  for (int t = blockIdx.x * 256 + tid; t < N_I; t += 64 * 256) mi = fmaxf(mi, nI[t]);
#pragma unroll
  for (int o = 32; o > 0; o >>= 1) {
    mu = fmaxf(mu, __shfl_down(mu, o, 64));
    mi = fmaxf(mi, __shfl_down(mi, o, 64));
  }
  if (lane == 0) { red[wv][0] = mu; red[wv][1] = mi; }
  __syncthreads();
  if (tid == 0) {
    float a = fmaxf(fmaxf(red[0][0], red[1][0]), fmaxf(red[2][0], red[3][0]));
    float b = fmaxf(fmaxf(red[0][1], red[1][1]), fmaxf(red[2][1], red[3][1]));
    atomMaxF(acc + 6, a);
    atomMaxF(acc + 7, b);
  }
}

// ---------------- gathered queries: pre-scaled split-bf16 + Cauchy-Schwarz offset M0 ----------------
__global__ void k_cvt_q(const float* __restrict__ sGu, const float* __restrict__ sGi,
                        const int* __restrict__ uids, const int* __restrict__ iids,
                        unsigned short* __restrict__ QuH, unsigned short* __restrict__ QuL,
                        unsigned short* __restrict__ QiH, unsigned short* __restrict__ QiL,
                        const float* __restrict__ acc,
                        float* __restrict__ M0u, float* __restrict__ M0i) {
  int lane = threadIdx.x & 63, wv = threadIdx.x >> 6;
  int row = blockIdx.x * 4 + wv;
  int side = row >> 11;
  int b = row & (B - 1);
  int id = side ? iids[b] : uids[b];
  float x = (side ? sGi : sGu)[(size_t)id * 64 + lane] * SCALE_LOG2;
  unsigned short hi = f2bf(x);
  unsigned short lo = f2bf(x - bf2f(hi));
  if (side) { QiH[(size_t)b * 64 + lane] = hi; QiL[(size_t)b * 64 + lane] = lo; }
  else      { QuH[(size_t)b * 64 + lane] = hi; QuL[(size_t)b * 64 + lane] = lo; }
  float n2 = wred(x * x);
  if (lane == 0) {
    float en2 = side ? acc[7] : acc[6];
    float M0 = sqrtf(n2) * sqrtf(en2) * 1.01f + 1.0f;
    (side ? M0i : M0u)[b] = M0;
  }
}

// ---------------- MFMA logsumexp: fixed offset, reg-dbuf, 128 queries/wave ----------------
// 8 q-tiles per wave -> 48 MFMA per 4 B-loads (2x arithmetic intensity vs 4-tile version).
// Grid (B/512, NSP) = (4,128) = 512 blocks = 2/CU. launch_bounds(256,2) caps VGPR at 256.
__global__ __launch_bounds__(256, 2) void k_lse_mfma(
    const unsigned short* __restrict__ Qhi, const unsigned short* __restrict__ Qlo,
    const unsigned short* __restrict__ Ehi, const unsigned short* __restrict__ Elo,
    const float* __restrict__ M0arr,
    int n_rows, int rows_per_split,
    float* __restrict__ part_s) {
  int tid = threadIdx.x;
  int wave = tid >> 6, lane = tid & 63;
  int l15 = lane & 15, quad = lane >> 4;
  int qbase = (blockIdx.x * 4 + wave) * 128;
  int split = blockIdx.y;
  int row0 = split * rows_per_split;
  int row_end = min(row0 + rows_per_split, n_rows);
  int rows = row_end - row0; if (rows < 0) rows = 0;
  int total = (rows + 15) >> 4;
  int ntail = rows & 15;

  float ss[8][4];
#pragma unroll
  for (int t = 0; t < 8; t++)
#pragma unroll
    for (int g = 0; g < 4; g++) ss[t][g] = 0.f;

  if (total > 0) {
    short8 ah[8][2], al[8][2];
#pragma unroll
    for (int t = 0; t < 8; t++)
#pragma unroll
      for (int c = 0; c < 2; c++) {
        size_t idx = (size_t)(qbase + t * 16 + l15) * 64 + c * 32 + quad * 8;
        ah[t][c] = *(const short8*)(Qhi + idx);
        al[t][c] = *(const short8*)(Qlo + idx);
      }

    f32x4 cinit[8];
#pragma unroll
    for (int t = 0; t < 8; t++)
#pragma unroll
      for (int g = 0; g < 4; g++)
        cinit[t][g] = -M0arr[qbase + t * 16 + quad * 4 + g];

    const unsigned short* ph = Ehi + (size_t)(row0 + l15) * 64 + quad * 8;
    const unsigned short* pl = Elo + (size_t)(row0 + l15) * 64 + quad * 8;

    short8 cb0 = *(const short8*)(ph);
    short8 cb1 = *(const short8*)(ph + 32);
    short8 cb2 = *(const short8*)(pl);
    short8 cb3 = *(const short8*)(pl + 32);
    ph += 1024; pl += 1024;

    for (int it = 0; it < total - 1; it++) {
      short8 nb0 = *(const short8*)(ph);
      short8 nb1 = *(const short8*)(ph + 32);
      short8 nb2 = *(const short8*)(pl);
      short8 nb3 = *(const short8*)(pl + 32);
      ph += 1024; pl += 1024;
#pragma unroll
      for (int t = 0; t < 8; t++) {
        f32x4 acc = cinit[t];
        acc = __builtin_amdgcn_mfma_f32_16x16x32_bf16(ah[t][0], cb0, acc, 0, 0, 0);
        acc = __builtin_amdgcn_mfma_f32_16x16x32_bf16(ah[t][1], cb1, acc, 0, 0, 0);
        acc = __builtin_amdgcn_mfma_f32_16x16x32_bf16(al[t][0], cb0, acc, 0, 0, 0);
        acc = __builtin_amdgcn_mfma_f32_16x16x32_bf16(al[t][1], cb1, acc, 0, 0, 0);
        acc = __builtin_amdgcn_mfma_f32_16x16x32_bf16(ah[t][0], cb2, acc, 0, 0, 0);
        acc = __builtin_amdgcn_mfma_f32_16x16x32_bf16(ah[t][1], cb3, acc, 0, 0, 0);
#pragma unroll
        for (int g = 0; g < 4; g++)
          ss[t][g] += exp2f(acc[g]);
      }
      cb0 = nb0; cb1 = nb1; cb2 = nb2; cb3 = nb3;
    }
    {  // last tile (masked iff ntail != 0)
      bool valid = (ntail == 0) || (l15 < ntail);
#pragma unroll
      for (int t = 0; t < 8; t++) {
        f32x4 acc = cinit[t];
        acc = __builtin_amdgcn_mfma_f32_16x16x32_bf16(ah[t][0], cb0, acc, 0, 0, 0);
        acc = __builtin_amdgcn_mfma_f32_16x16x32_bf16(ah[t][1], cb1, acc, 0, 0, 0);
        acc = __builtin_amdgcn_mfma_f32_16x16x32_bf16(al[t][0], cb0, acc, 0, 0, 0);
        acc = __builtin_amdgcn_mfma_f32_16x16x32_bf16(al[t][1], cb1, acc, 0, 0, 0);
        acc = __builtin_amdgcn_mfma_f32_16x16x32_bf16(ah[t][0], cb2, acc, 0, 0, 0);
        acc = __builtin_amdgcn_mfma_f32_16x16x32_bf16(ah[t][1], cb3, acc, 0, 0, 0);
#pragma unroll
        for (int g = 0; g < 4; g++) {
          float e = exp2f(acc[g]);
          ss[t][g] += valid ? e : 0.f;
        }
      }
    }
  }

#pragma unroll
  for (int off = 1; off < 16; off <<= 1) {
#pragma unroll
    for (int t = 0; t < 8; t++)
#pragma unroll
      for (int g = 0; g < 4; g++)
        ss[t][g] += __shfl_xor(ss[t][g], off, 64);
  }

  if (l15 == 0) {
#pragma unroll
    for (int t = 0; t < 8; t++)
#pragma unroll
      for (int g = 0; g < 4; g++) {
        int q = qbase + t * 16 + quad * 4 + g;
        part_s[(size_t)split * B + q] = ss[t][g];
      }
  }
}

// ---------------- L2 regularization reduce ----------------
__global__ void k_reg(const float* __restrict__ Eu0, const float* __restrict__ Ei0, float* acc) {
  __shared__ float red[4];
  int tid = threadIdx.x;
  float s = 0.f;
  const float4* A = (const float4*)Eu0;
  const float4* Bp = (const float4*)Ei0;
  const int nA = N_U * 16, nTot = N_TOT * 16;
  for (int t = blockIdx.x * 256 + tid; t < nTot; t += 256 * 256) {
    float4 v = (t < nA) ? A[t] : Bp[t - nA];
    s += v.x * v.x + v.y * v.y + v.z * v.z + v.w * v.w;
  }
  s = wred(s);
  if ((tid & 63) == 0) red[tid >> 6] = s;
  __syncthreads();
  if (tid == 0) unsafeAtomicAdd(acc + 5, red[0] + red[1] + red[2] + red[3]);
}

// ---------------- per-sample losses ----------------
__global__ void k_small(const float* __restrict__ sEu, const float* __restrict__ sEi,
                        const float* __restrict__ sGu, const float* __restrict__ sGi,
                        const int* __restrict__ uids, const int* __restrict__ iids,
                        const int* __restrict__ pos, const int* __restrict__ neg,
                        const float* __restrict__ psU, const float* __restrict__ psI,
                        const float* __restrict__ M0u, const float* __restrict__ M0i,
                        float* acc) {
  int b = blockIdx.x * 256 + threadIdx.x;
  float du = 0.f, di = 0.f, nu = 0.f, ni = 0.f, bpr = 0.f;
  if (b < B) {
    float su = 0.f, si = 0.f;
    for (int s2 = 0; s2 < NSP; s2++) su += psU[(size_t)s2 * B + b];
    for (int s2 = 0; s2 < NSP; s2++) si += psI[(size_t)s2 * B + b];
    float lseu = M0u[b] * LN2F + logf(su);
    float lsei = M0i[b] * LN2F + logf(si);
    nu = fmaxf(lseu, LOG_EPS) + log1pf(expf(-fabsf(lseu - LOG_EPS)));
    ni = fmaxf(lsei, LOG_EPS) + log1pf(expf(-fabsf(lsei - LOG_EPS)));

    int u = uids[b], it = iids[b], p = pos[b], ng = neg[b];
    const float4* gu = (const float4*)(sGu + (size_t)u * D);
    const float4* eu = (const float4*)(sEu + (size_t)u * D);
    const float4* gi = (const float4*)(sGi + (size_t)it * D);
    const float4* ei = (const float4*)(sEi + (size_t)it * D);
    const float4* ep = (const float4*)(sEi + (size_t)p * D);
    const float4* en = (const float4*)(sEi + (size_t)ng * D);
    float diff = 0.f;
#pragma unroll
    for (int k = 0; k < 16; k++) {
      float4 a = gu[k], b4 = eu[k];
      du += a.x * b4.x + a.y * b4.y + a.z * b4.z + a.w * b4.w;
      float4 c = gi[k], d4 = ei[k];
      di += c.x * d4.x + c.y * d4.y + c.z * d4.z + c.w * d4.w;
      float4 e = ep[k], f = en[k];
      diff += b4.x * (e.x - f.x) + b4.y * (e.y - f.y) + b4.z * (e.z - f.z) + b4.w * (e.w - f.w);
    }
    bpr = (diff > 0.f) ? log1pf(expf(-diff)) : (-diff + log1pf(expf(diff)));
  }
  du = wred(du); di = wred(di); nu = wred(nu); ni = wred(ni); bpr = wred(bpr);
  if ((threadIdx.x & 63) == 0) {
    unsafeAtomicAdd(acc + 0, du);
    unsafeAtomicAdd(acc + 1, di);
    unsafeAtomicAdd(acc + 2, nu);
    unsafeAtomicAdd(acc + 3, ni);
    unsafeAtomicAdd(acc + 4, bpr);
  }
}

// ---------------- finalize ----------------
__global__ void k_final(const float* __restrict__ acc, float* __restrict__ out) {
  float pos_score = (acc[0] + acc[1]) * (INV_TEMP / (float)B);
  float neg_score = (acc[2] + acc[3]) / (float)B;
  float loss_s = neg_score - pos_score;
  float loss_r = acc[4] / (float)B;
  float reg = LAMBDA2 * acc[5];
  out[0] = loss_r + LAMBDA1 * loss_s + reg;
  out[1] = loss_r;
  out[2] = LAMBDA1 * loss_s;
}

extern "C" void kernel_launch(void* const* d_in, const int* in_sizes, int n_in,
                              void* d_out, int out_size, void* d_ws, size_t ws_size,
                              hipStream_t stream) {
  const float* Eu0  = (const float*)d_in[0];
  const float* Ei0  = (const float*)d_in[1];
  const float* vals = (const float*)d_in[2];
  const float* W    = (const float*)d_in[3];
  const float* al   = (const float*)d_in[4];
  const float* ar   = (const float*)d_in[5];
  const int* ii     = (const int*)d_in[7];
  const int* uids   = (const int*)d_in[10];
  const int* iids   = (const int*)d_in[11];
  const int* pos    = (const int*)d_in[12];
  const int* neg    = (const int*)d_in[13];
  float* out = (float*)d_out;

  char* base = (char*)d_ws;
  size_t off = 0;
  auto alloc = [&](size_t bytes) -> void* {
    void* p = base + off;
    off = (off + bytes + 255) & ~(size_t)255;
    return p;
  };
  float* fU_a = (float*)alloc((size_t)N_U * 128 * 4);
  float* fU_b = (float*)alloc((size_t)N_U * 128 * 4);
  float* fI_a = (float*)alloc((size_t)N_I * 128 * 4);
  float* fI_b = (float*)alloc((size_t)N_I * 128 * 4);
  float* sEu  = (float*)alloc((size_t)N_U * D * 4);
  float* sEi  = (float*)alloc((size_t)N_I * D * 4);
  float* sGu  = (float*)alloc((size_t)N_U * D * 4);
  float* sGi  = (float*)alloc((size_t)N_I * D * 4);
  float* el   = (float*)alloc((size_t)N_TOT * 4 * 4);
  float* er   = (float*)alloc((size_t)N_TOT * 4 * 4);
  float* psU  = (float*)alloc((size_t)B * NSP * 4);
  float* psI  = (float*)alloc((size_t)B * NSP * 4);
  float* M0u  = (float*)alloc((size_t)B * 4);
  float* M0i  = (float*)alloc((size_t)B * 4);
  float* normU= (float*)alloc((size_t)N_U * 4);
  float* normI= (float*)alloc((size_t)N_I * 4);
  float* acc  = (float*)alloc(16 * 4);
  int* deg    = (int*)alloc((size_t)N_I * 4);
  int* cursor = (int*)alloc((size_t)N_I * 4);
  int* rowptr = (int*)alloc((size_t)(N_I + 1) * 4);
  int* u_srt  = (int*)alloc((size_t)NNZ * 4);
  float* v_srt= (float*)alloc((size_t)NNZ * 4);
  unsigned short* EuH = (unsigned short*)alloc((size_t)PAD_U * 64 * 2);
  unsigned short* EuL = (unsigned short*)alloc((size_t)PAD_U * 64 * 2);
  unsigned short* EiH = (unsigned short*)alloc((size_t)PAD_I * 64 * 2);
  unsigned short* EiL = (unsigned short*)alloc((size_t)PAD_I * 64 * 2);
  unsigned short* QuH = (unsigned short*)alloc((size_t)B * 64 * 2);
  unsigned short* QuL = (unsigned short*)alloc((size_t)B * 64 * 2);
  unsigned short* QiH = (unsigned short*)alloc((size_t)B * 64 * 2);
  unsigned short* QiL = (unsigned short*)alloc((size_t)B * 64 * 2);

  k_init<<<(N_TOT * D + 255) / 256, 256, 0, stream>>>(Eu0, Ei0, fU_a, fI_a, sEu, sEi, sGu, sGi,
                                                      deg, acc);
  k_deg<<<(NNZ + 255) / 256, 256, 0, stream>>>(ii, deg);
  k_scan<<<1, 1024, 0, stream>>>(deg, rowptr, cursor);
  k_fill<<<(NNZ + 255) / 256, 256, 0, stream>>>(ii, vals, cursor, u_srt, v_srt);

  float* cu = fU_a; float* ci = fI_a;
  float* nu = fU_b; float* ni = fI_b;
  for (int l = 0; l < 2; ++l) {
    float* elmx = acc + 8 + 4 * l;
    bool last = (l == 1);
    k_feat<<<(N_TOT + 15) / 16, 256, 0, stream>>>(cu, ci, W, al, ar, el, er);
    k_elmax<<<64, 256, 0, stream>>>(el, elmx);
    k_user_layer<<<(N_U * D) / 256, 256, 0, stream>>>(cu, ci, el, er, vals, ii, elmx, nu, sEu, sGu,
                                                      last ? EuH : nullptr, last ? EuL : nullptr,
                                                      normU);
    k_item_layer<<<(N_I * D) / 256, 256, 0, stream>>>(cu, ci, el, er, rowptr, u_srt, v_srt, elmx,
                                                      ni, sEi, sGi,
                                                      last ? EiH : nullptr, last ? EiL : nullptr,
                                                      normI);
    float* t1 = cu; cu = nu; nu = t1;
    float* t2 = ci; ci = ni; ni = t2;
  }

  k_norm_max<<<64, 256, 0, stream>>>(normU, normI, acc);
  k_cvt_q<<<(2 * B) / 4, 256, 0, stream>>>(sGu, sGi, uids, iids, QuH, QuL, QiH, QiL, acc, M0u, M0i);
  k_lse_mfma<<<dim3(B / 512, NSP), 256, 0, stream>>>(QuH, QuL, EuH, EuL, M0u, N_U, RSP_U, psU);
  k_lse_mfma<<<dim3(B / 512, NSP), 256, 0, stream>>>(QiH, QiL, EiH, EiL, M0i, N_I, RSP_I, psI);
  k_reg<<<256, 256, 0, stream>>>(Eu0, Ei0, acc);
  k_small<<<B / 256, 256, 0, stream>>>(sEu, sEi, sGu, sGi, uids, iids, pos, neg,
                                       psU, psI, M0u, M0i, acc);
  k_final<<<1, 1, 0, stream>>>(acc, out);
}

// Round 14
// 445.963 us; speedup vs baseline: 1.1114x; 1.0412x over previous
//
#include <hip/hip_runtime.h>
#include <math.h>

#define N_U 30000
#define N_I 15000
#define N_TOT 45000
#define D 64
#define NNZ 480000
#define B 2048
#define INV_TEMP 5.0f
#define LOG_EPS -18.420680743952367f
#define NEG_SLOPE 0.2f
#define LAMBDA1 0.2f
#define LAMBDA2 1e-7f

// MFMA-lse config
#define NSP 128
#define RSP_U 235
#define RSP_I 118
#define PAD_U 30016
#define PAD_I 15040
#define SCALE_LOG2 7.2134752044448170f
#define LN2F 0.6931471805599453f

typedef __attribute__((ext_vector_type(8))) short short8;
typedef __attribute__((ext_vector_type(4))) float f32x4;

__device__ inline float wred(float v) {
#pragma unroll
  for (int o = 32; o > 0; o >>= 1) v += __shfl_down(v, o, 64);
  return v;
}

__device__ inline float leaky(float v) { return (v >= 0.f) ? v : NEG_SLOPE * v; }

__device__ inline void atomMaxF(float* a, float v) {
  if (v >= 0.f) atomicMax((int*)a, __float_as_int(v));
  else atomicMin((unsigned int*)a, __float_as_uint(v));
}

__device__ inline unsigned short f2bf(float x) {
  unsigned u = __float_as_uint(x);
  unsigned r = u + 0x7FFFu + ((u >> 16) & 1u);
  return (unsigned short)(r >> 16);
}
__device__ inline float bf2f(unsigned short h) {
  return __uint_as_float(((unsigned)h) << 16);
}

// ---------------- init ----------------
__global__ void k_init(const float* __restrict__ Eu0, const float* __restrict__ Ei0,
                       float* fU, float* fI, float* sEu, float* sEi,
                       float* sGu, float* sGi, int* deg, float* acc) {
  int t = blockIdx.x * 256 + threadIdx.x;
  if (t < 16) acc[t] = (t >= 8) ? -INFINITY : 0.f;
  if (t < N_I) deg[t] = 0;
  if (t < N_U * D) {
    int n = t >> 6, c = t & 63;
    float v = Eu0[t];
    fU[(size_t)n * 128 + c] = v;
    sEu[t] = v; sGu[t] = v;
  } else if (t < N_TOT * D) {
    int j = t - N_U * D;
    int n = j >> 6, c = j & 63;
    float v = Ei0[j];
    fI[(size_t)n * 128 + c] = v;
    sEi[j] = v; sGi[j] = v;
  }
}

// ---------------- CSR build over item side ----------------
__global__ void k_deg(const int* __restrict__ ii, int* deg) {
  int e = blockIdx.x * 256 + threadIdx.x;
  if (e < NNZ) atomicAdd(&deg[ii[e]], 1);
}

// single block of 1024: thread t serially scans its 15-element chunk; one block-scan of thread sums
__global__ void k_scan(const int* __restrict__ deg, int* rowptr, int* cursor) {
  __shared__ int tsum[1024];
  const int CHUNK = 15;  // 1024*15 = 15360 >= N_I
  int tid = threadIdx.x;
  int base = tid * CHUNK;
  int s = 0;
#pragma unroll
  for (int k = 0; k < CHUNK; k++) {
    int idx = base + k;
    s += (idx < N_I) ? deg[idx] : 0;
  }
  tsum[tid] = s;
  __syncthreads();
  for (int o = 1; o < 1024; o <<= 1) {
    int x = (tid >= o) ? tsum[tid - o] : 0;
    __syncthreads();
    tsum[tid] += x;
    __syncthreads();
  }
  int excl = tsum[tid] - s;  // exclusive prefix of this chunk
#pragma unroll
  for (int k = 0; k < CHUNK; k++) {
    int idx = base + k;
    if (idx < N_I) {
      rowptr[idx] = excl;
      cursor[idx] = excl;
      excl += deg[idx];
    }
  }
  if (tid == 1023) rowptr[N_I] = tsum[1023];
}

__global__ void k_fill(const int* __restrict__ ii, const float* __restrict__ vals,
                       int* cursor, int* u_srt, float* v_srt) {
  int e = blockIdx.x * 256 + threadIdx.x;
  if (e < NNZ) {
    int pos = atomicAdd(&cursor[ii[e]], 1);
    u_srt[pos] = e >> 4;
    v_srt[pos] = vals[e];
  }
}

// ---------------- GAT: feat = E @ W into fused[64:128], el/er ----------------
__global__ void k_feat(float* __restrict__ fU, float* __restrict__ fI,
                       const float* __restrict__ W, const float* __restrict__ al,
                       const float* __restrict__ ar,
                       float* __restrict__ el, float* __restrict__ er) {
  __shared__ float Ws[64 * 64];
  __shared__ float hs[16][64];
  int tid = threadIdx.x;
  for (int t = tid; t < 1024; t += 256) ((float4*)Ws)[t] = ((const float4*)W)[t];
  int g = tid >> 6, c = tid & 63;
  int n0 = blockIdx.x * 16 + g * 4;
  float* rows[4];
#pragma unroll
  for (int j = 0; j < 4; j++) {
    int node = n0 + j;
    rows[j] = nullptr;
    if (node < N_TOT) {
      rows[j] = (node < N_U) ? (fU + (size_t)node * 128) : (fI + (size_t)(node - N_U) * 128);
      hs[g * 4 + j][c] = rows[j][c];
    }
  }
  __syncthreads();
  float a0 = 0.f, a1 = 0.f, a2 = 0.f, a3 = 0.f;
#pragma unroll 8
  for (int k = 0; k < 64; ++k) {
    float w = Ws[k * 64 + c];
    a0 = fmaf(hs[g * 4 + 0][k], w, a0);
    a1 = fmaf(hs[g * 4 + 1][k], w, a1);
    a2 = fmaf(hs[g * 4 + 2][k], w, a2);
    a3 = fmaf(hs[g * 4 + 3][k], w, a3);
  }
  float accs[4] = {a0, a1, a2, a3};
  float alc = al[c], arc = ar[c];
#pragma unroll
  for (int j = 0; j < 4; j++) {
    int node = n0 + j;
    if (node >= N_TOT) continue;
    rows[j][64 + c] = accs[j];
    float pl = accs[j] * alc;
    float pr = accs[j] * arc;
#pragma unroll
    for (int o = 8; o >= 1; o >>= 1) {
      pl += __shfl_down(pl, o, 16);
      pr += __shfl_down(pr, o, 16);
    }
    if ((c & 15) == 0) {
      el[node * 4 + (c >> 4)] = pl;
      er[node * 4 + (c >> 4)] = pr;
    }
  }
}

// ---------------- per-head global max of el ----------------
__global__ void k_elmax(const float* __restrict__ el, float* __restrict__ dst) {
  __shared__ float red[4][4];
  int tid = threadIdx.x;
  int lane = tid & 63, wv = tid >> 6;
  float mx = -INFINITY;
  for (int t = blockIdx.x * 256 + tid; t < N_TOT * 4; t += 64 * 256)
    mx = fmaxf(mx, el[t]);
#pragma unroll
  for (int o = 4; o < 64; o <<= 1) mx = fmaxf(mx, __shfl_xor(mx, o, 64));
  if (lane < 4) red[wv][lane] = mx;
  __syncthreads();
  if (tid < 4) {
    float m2 = fmaxf(fmaxf(red[0][tid], red[1][tid]), fmaxf(red[2][tid], red[3][tid]));
    atomMaxF(dst + tid, m2);
  }
}

// ---------------- fused graph layer: user path + item path in one dispatch ----------------
__global__ void k_layer(const float* __restrict__ fU_cur, const float* __restrict__ fI_cur,
                        const float* __restrict__ el, const float* __restrict__ er,
                        const float* __restrict__ vals, const int* __restrict__ ii,
                        const int* __restrict__ rowptr, const int* __restrict__ u_srt,
                        const float* __restrict__ v_srt,
                        const float* __restrict__ elmx,
                        float* __restrict__ fU_nxt, float* __restrict__ fI_nxt,
                        float* __restrict__ sEu, float* __restrict__ sEi,
                        float* __restrict__ sGu, float* __restrict__ sGi,
                        unsigned short* __restrict__ EuH, unsigned short* __restrict__ EuL,
                        unsigned short* __restrict__ EiH, unsigned short* __restrict__ EiL,
                        float* __restrict__ normU, float* __restrict__ normI) {
  int t = blockIdx.x * 256 + threadIdx.x;
  int node = t >> 6, c = t & 63;
  if (node >= N_TOT) return;
  int h = c >> 4;

  if (node < N_U) {
    int u = node;
    float eru = er[u * 4 + h];
    float m = leaky(elmx[h] + eru);
    const float* selfrow = fU_cur + (size_t)u * 128;
    float aself = __expf(leaky(el[u * 4 + h] + eru) - m);

    int idx[16]; float vv[16];
#pragma unroll
    for (int k = 0; k < 16; k++) { idx[k] = ii[u * 16 + k]; vv[k] = vals[u * 16 + k]; }
    float av[16];
#pragma unroll
    for (int k = 0; k < 16; k++)
      av[k] = __expf(leaky(el[(idx[k] + N_U) * 4 + h] + eru) - m);

    float den = aself;
#pragma unroll
    for (int k = 0; k < 16; k++) den += av[k];

    float o0 = aself * selfrow[64 + c], o1 = 0.f;
    float z0 = 0.f, z1 = 0.f;
#pragma unroll
    for (int k = 0; k < 16; k += 2) {
      const float* rA = fI_cur + (size_t)idx[k] * 128;
      const float* rB = fI_cur + (size_t)idx[k + 1] * 128;
      float eA = rA[c], fA = rA[64 + c];
      float eB = rB[c], fB = rB[64 + c];
      z0 = fmaf(vv[k], eA, z0);
      z1 = fmaf(vv[k + 1], eB, z1);
      o0 = fmaf(av[k], fA, o0);
      o1 = fmaf(av[k + 1], fB, o1);
    }
    float o = (o0 + o1) / den;
    float g = (o > 0.f) ? o : expm1f(o);
    float e_new = selfrow[c] + z0 + z1;
    fU_nxt[(size_t)u * 128 + c] = e_new;
    size_t off = (size_t)u * D + c;
    float s_final = sEu[off] + e_new;
    sEu[off] = s_final;
    sGu[off] += g;
    if (EuH) {
      unsigned short hi = f2bf(s_final);
      EuH[off] = hi;
      EuL[off] = f2bf(s_final - bf2f(hi));
      float n2 = wred(s_final * s_final);
      if (c == 0) normU[u] = n2;
    }
  } else {
    int i = node - N_U;
    float eri = er[node * 4 + h];
    float m = leaky(elmx[h] + eri);
    const float* selfrow = fI_cur + (size_t)i * 128;
    float aself = __expf(leaky(el[node * 4 + h] + eri) - m);
    float den0 = aself, den1 = 0.f;
    float o0 = aself * selfrow[64 + c], o1 = 0.f;
    float z0 = 0.f, z1 = 0.f;
    int r0 = rowptr[i], r1 = rowptr[i + 1];
    int r = r0;
    for (; r + 3 < r1; r += 4) {
      int u0 = u_srt[r], u1 = u_srt[r + 1], u2 = u_srt[r + 2], u3 = u_srt[r + 3];
      float v0 = v_srt[r], v1 = v_srt[r + 1], v2 = v_srt[r + 2], v3 = v_srt[r + 3];
      float a0 = __expf(leaky(el[u0 * 4 + h] + eri) - m);
      float a1 = __expf(leaky(el[u1 * 4 + h] + eri) - m);
      float a2 = __expf(leaky(el[u2 * 4 + h] + eri) - m);
      float a3 = __expf(leaky(el[u3 * 4 + h] + eri) - m);
      const float* R0 = fU_cur + (size_t)u0 * 128;
      const float* R1 = fU_cur + (size_t)u1 * 128;
      const float* R2 = fU_cur + (size_t)u2 * 128;
      const float* R3 = fU_cur + (size_t)u3 * 128;
      float e0 = R0[c], f0 = R0[64 + c];
      float e1 = R1[c], f1 = R1[64 + c];
      float e2 = R2[c], f2 = R2[64 + c];
      float e3 = R3[c], f3 = R3[64 + c];
      z0 = fmaf(v0, e0, z0); z1 = fmaf(v1, e1, z1);
      z0 = fmaf(v2, e2, z0); z1 = fmaf(v3, e3, z1);
      den0 += a0 + a2; den1 += a1 + a3;
      o0 = fmaf(a0, f0, o0); o1 = fmaf(a1, f1, o1);
      o0 = fmaf(a2, f2, o0); o1 = fmaf(a3, f3, o1);
    }
    for (; r < r1; r++) {
      int u0 = u_srt[r];
      float v0 = v_srt[r];
      float a0 = __expf(leaky(el[u0 * 4 + h] + eri) - m);
      const float* R0 = fU_cur + (size_t)u0 * 128;
      float e0 = R0[c], f0 = R0[64 + c];
      z0 = fmaf(v0, e0, z0);
      den0 += a0;
      o0 = fmaf(a0, f0, o0);
    }
    float o = (o0 + o1) / (den0 + den1);
    float g = (o > 0.f) ? o : expm1f(o);
    float e_new = selfrow[c] + z0 + z1;
    fI_nxt[(size_t)i * 128 + c] = e_new;
    size_t off = (size_t)i * D + c;
    float s_final = sEi[off] + e_new;
    sEi[off] = s_final;
    sGi[off] += g;
    if (EiH) {
      unsigned short hi = f2bf(s_final);
      EiH[off] = hi;
      EiL[off] = f2bf(s_final - bf2f(hi));
      float n2 = wred(s_final * s_final);
      if (c == 0) normI[i] = n2;
    }
  }
}

// ---------------- max row-norm reduce + L2 reg reduce (fused) ----------------
__global__ void k_normreg(const float* __restrict__ nU, const float* __restrict__ nI,
                          const float* __restrict__ Eu0, const float* __restrict__ Ei0,
                          float* __restrict__ acc) {
  __shared__ float red[4][3];
  int tid = threadIdx.x;
  int lane = tid & 63, wv = tid >> 6;
  float mu = 0.f, mi = 0.f, s = 0.f;
  for (int t = blockIdx.x * 256 + tid; t < N_U; t += 128 * 256) mu = fmaxf(mu, nU[t]);
  for (int t = blockIdx.x * 256 + tid; t < N_I; t += 128 * 256) mi = fmaxf(mi, nI[t]);
  const float4* A = (const float4*)Eu0;
  const float4* Bp = (const float4*)Ei0;
  const int nA = N_U * 16, nTot = N_TOT * 16;
  for (int t = blockIdx.x * 256 + tid; t < nTot; t += 128 * 256) {
    float4 v = (t < nA) ? A[t] : Bp[t - nA];
    s += v.x * v.x + v.y * v.y + v.z * v.z + v.w * v.w;
  }
#pragma unroll
  for (int o = 32; o > 0; o >>= 1) {
    mu = fmaxf(mu, __shfl_down(mu, o, 64));
    mi = fmaxf(mi, __shfl_down(mi, o, 64));
    s += __shfl_down(s, o, 64);
  }
  if (lane == 0) { red[wv][0] = mu; red[wv][1] = mi; red[wv][2] = s; }
  __syncthreads();
  if (tid == 0) {
    float a = fmaxf(fmaxf(red[0][0], red[1][0]), fmaxf(red[2][0], red[3][0]));
    float b = fmaxf(fmaxf(red[0][1], red[1][1]), fmaxf(red[2][1], red[3][1]));
    float ssum = red[0][2] + red[1][2] + red[2][2] + red[3][2];
    atomMaxF(acc + 6, a);
    atomMaxF(acc + 7, b);
    unsafeAtomicAdd(acc + 5, ssum);
  }
}

// ---------------- gathered queries: pre-scaled split-bf16 + Cauchy-Schwarz offset M0 ----------------
__global__ void k_cvt_q(const float* __restrict__ sGu, const float* __restrict__ sGi,
                        const int* __restrict__ uids, const int* __restrict__ iids,
                        unsigned short* __restrict__ QuH, unsigned short* __restrict__ QuL,
                        unsigned short* __restrict__ QiH, unsigned short* __restrict__ QiL,
                        const float* __restrict__ acc,
                        float* __restrict__ M0u, float* __restrict__ M0i) {
  int lane = threadIdx.x & 63, wv = threadIdx.x >> 6;
  int row = blockIdx.x * 4 + wv;
  int side = row >> 11;
  int b = row & (B - 1);
  int id = side ? iids[b] : uids[b];
  float x = (side ? sGi : sGu)[(size_t)id * 64 + lane] * SCALE_LOG2;
  unsigned short hi = f2bf(x);
  unsigned short lo = f2bf(x - bf2f(hi));
  if (side) { QiH[(size_t)b * 64 + lane] = hi; QiL[(size_t)b * 64 + lane] = lo; }
  else      { QuH[(size_t)b * 64 + lane] = hi; QuL[(size_t)b * 64 + lane] = lo; }
  float n2 = wred(x * x);
  if (lane == 0) {
    float en2 = side ? acc[7] : acc[6];
    float M0 = sqrtf(n2) * sqrtf(en2) * 1.01f + 1.0f;
    (side ? M0i : M0u)[b] = M0;
  }
}

// ---------------- MFMA logsumexp: both sides in one dispatch (blockIdx.z) ----------------
__global__ __launch_bounds__(256, 2) void k_lse_mfma(
    const unsigned short* __restrict__ QuH, const unsigned short* __restrict__ QuL,
    const unsigned short* __restrict__ EuHp, const unsigned short* __restrict__ EuLp,
    const unsigned short* __restrict__ QiH, const unsigned short* __restrict__ QiL,
    const unsigned short* __restrict__ EiHp, const unsigned short* __restrict__ EiLp,
    const float* __restrict__ M0u, const float* __restrict__ M0i,
    float* __restrict__ psU, float* __restrict__ psI) {
  int z = blockIdx.z;
  const unsigned short* Qhi = z ? QiH : QuH;
  const unsigned short* Qlo = z ? QiL : QuL;
  const unsigned short* Ehi = z ? EiHp : EuHp;
  const unsigned short* Elo = z ? EiLp : EuLp;
  const float* M0arr = z ? M0i : M0u;
  float* part_s = z ? psI : psU;
  int n_rows = z ? N_I : N_U;
  int rows_per_split = z ? RSP_I : RSP_U;

  int tid = threadIdx.x;
  int wave = tid >> 6, lane = tid & 63;
  int l15 = lane & 15, quad = lane >> 4;
  int qbase = (blockIdx.x * 4 + wave) * 128;
  int split = blockIdx.y;
  int row0 = split * rows_per_split;
  int row_end = min(row0 + rows_per_split, n_rows);
  int rows = row_end - row0; if (rows < 0) rows = 0;
  int total = (rows + 15) >> 4;
  int ntail = rows & 15;

  float ss[8][4];
#pragma unroll
  for (int t = 0; t < 8; t++)
#pragma unroll
    for (int g = 0; g < 4; g++) ss[t][g] = 0.f;

  if (total > 0) {
    short8 ah[8][2], al[8][2];
#pragma unroll
    for (int t = 0; t < 8; t++)
#pragma unroll
      for (int c = 0; c < 2; c++) {
        size_t idx = (size_t)(qbase + t * 16 + l15) * 64 + c * 32 + quad * 8;
        ah[t][c] = *(const short8*)(Qhi + idx);
        al[t][c] = *(const short8*)(Qlo + idx);
      }

    f32x4 cinit[8];
#pragma unroll
    for (int t = 0; t < 8; t++)
#pragma unroll
      for (int g = 0; g < 4; g++)
        cinit[t][g] = -M0arr[qbase + t * 16 + quad * 4 + g];

    const unsigned short* ph = Ehi + (size_t)(row0 + l15) * 64 + quad * 8;
    const unsigned short* pl = Elo + (size_t)(row0 + l15) * 64 + quad * 8;

    short8 cb0 = *(const short8*)(ph);
    short8 cb1 = *(const short8*)(ph + 32);
    short8 cb2 = *(const short8*)(pl);
    short8 cb3 = *(const short8*)(pl + 32);
    ph += 1024; pl += 1024;

    for (int it = 0; it < total - 1; it++) {
      short8 nb0 = *(const short8*)(ph);
      short8 nb1 = *(const short8*)(ph + 32);
      short8 nb2 = *(const short8*)(pl);
      short8 nb3 = *(const short8*)(pl + 32);
      ph += 1024; pl += 1024;
#pragma unroll
      for (int t = 0; t < 8; t++) {
        f32x4 acc = cinit[t];
        acc = __builtin_amdgcn_mfma_f32_16x16x32_bf16(ah[t][0], cb0, acc, 0, 0, 0);
        acc = __builtin_amdgcn_mfma_f32_16x16x32_bf16(ah[t][1], cb1, acc, 0, 0, 0);
        acc = __builtin_amdgcn_mfma_f32_16x16x32_bf16(al[t][0], cb0, acc, 0, 0, 0);
        acc = __builtin_amdgcn_mfma_f32_16x16x32_bf16(al[t][1], cb1, acc, 0, 0, 0);
        acc = __builtin_amdgcn_mfma_f32_16x16x32_bf16(ah[t][0], cb2, acc, 0, 0, 0);
        acc = __builtin_amdgcn_mfma_f32_16x16x32_bf16(ah[t][1], cb3, acc, 0, 0, 0);
#pragma unroll
        for (int g = 0; g < 4; g++)
          ss[t][g] += exp2f(acc[g]);
      }
      cb0 = nb0; cb1 = nb1; cb2 = nb2; cb3 = nb3;
    }
    {
      bool valid = (ntail == 0) || (l15 < ntail);
#pragma unroll
      for (int t = 0; t < 8; t++) {
        f32x4 acc = cinit[t];
        acc = __builtin_amdgcn_mfma_f32_16x16x32_bf16(ah[t][0], cb0, acc, 0, 0, 0);
        acc = __builtin_amdgcn_mfma_f32_16x16x32_bf16(ah[t][1], cb1, acc, 0, 0, 0);
        acc = __builtin_amdgcn_mfma_f32_16x16x32_bf16(al[t][0], cb0, acc, 0, 0, 0);
        acc = __builtin_amdgcn_mfma_f32_16x16x32_bf16(al[t][1], cb1, acc, 0, 0, 0);
        acc = __builtin_amdgcn_mfma_f32_16x16x32_bf16(ah[t][0], cb2, acc, 0, 0, 0);
        acc = __builtin_amdgcn_mfma_f32_16x16x32_bf16(ah[t][1], cb3, acc, 0, 0, 0);
#pragma unroll
        for (int g = 0; g < 4; g++) {
          float e = exp2f(acc[g]);
          ss[t][g] += valid ? e : 0.f;
        }
      }
    }
  }

#pragma unroll
  for (int off = 1; off < 16; off <<= 1) {
#pragma unroll
    for (int t = 0; t < 8; t++)
#pragma unroll
      for (int g = 0; g < 4; g++)
        ss[t][g] += __shfl_xor(ss[t][g], off, 64);
  }

  if (l15 == 0) {
#pragma unroll
    for (int t = 0; t < 8; t++)
#pragma unroll
      for (int g = 0; g < 4; g++) {
        int q = qbase + t * 16 + quad * 4 + g;
        part_s[(size_t)split * B + q] = ss[t][g];
      }
  }
}

// ---------------- per-sample losses ----------------
__global__ void k_small(const float* __restrict__ sEu, const float* __restrict__ sEi,
                        const float* __restrict__ sGu, const float* __restrict__ sGi,
                        const int* __restrict__ uids, const int* __restrict__ iids,
                        const int* __restrict__ pos, const int* __restrict__ neg,
                        const float* __restrict__ psU, const float* __restrict__ psI,
                        const float* __restrict__ M0u, const float* __restrict__ M0i,
                        float* acc) {
  int b = blockIdx.x * 256 + threadIdx.x;
  float du = 0.f, di = 0.f, nu = 0.f, ni = 0.f, bpr = 0.f;
  if (b < B) {
    float su = 0.f, si = 0.f;
    for (int s2 = 0; s2 < NSP; s2++) su += psU[(size_t)s2 * B + b];
    for (int s2 = 0; s2 < NSP; s2++) si += psI[(size_t)s2 * B + b];
    float lseu = M0u[b] * LN2F + logf(su);
    float lsei = M0i[b] * LN2F + logf(si);
    nu = fmaxf(lseu, LOG_EPS) + log1pf(expf(-fabsf(lseu - LOG_EPS)));
    ni = fmaxf(lsei, LOG_EPS) + log1pf(expf(-fabsf(lsei - LOG_EPS)));

    int u = uids[b], it = iids[b], p = pos[b], ng = neg[b];
    const float4* gu = (const float4*)(sGu + (size_t)u * D);
    const float4* eu = (const float4*)(sEu + (size_t)u * D);
    const float4* gi = (const float4*)(sGi + (size_t)it * D);
    const float4* ei = (const float4*)(sEi + (size_t)it * D);
    const float4* ep = (const float4*)(sEi + (size_t)p * D);
    const float4* en = (const float4*)(sEi + (size_t)ng * D);
    float diff = 0.f;
#pragma unroll
    for (int k = 0; k < 16; k++) {
      float4 a = gu[k], b4 = eu[k];
      du += a.x * b4.x + a.y * b4.y + a.z * b4.z + a.w * b4.w;
      float4 c = gi[k], d4 = ei[k];
      di += c.x * d4.x + c.y * d4.y + c.z * d4.z + c.w * d4.w;
      float4 e = ep[k], f = en[k];
      diff += b4.x * (e.x - f.x) + b4.y * (e.y - f.y) + b4.z * (e.z - f.z) + b4.w * (e.w - f.w);
    }
    bpr = (diff > 0.f) ? log1pf(expf(-diff)) : (-diff + log1pf(expf(diff)));
  }
  du = wred(du); di = wred(di); nu = wred(nu); ni = wred(ni); bpr = wred(bpr);
  if ((threadIdx.x & 63) == 0) {
    unsafeAtomicAdd(acc + 0, du);
    unsafeAtomicAdd(acc + 1, di);
    unsafeAtomicAdd(acc + 2, nu);
    unsafeAtomicAdd(acc + 3, ni);
    unsafeAtomicAdd(acc + 4, bpr);
  }
}

// ---------------- finalize ----------------
__global__ void k_final(const float* __restrict__ acc, float* __restrict__ out) {
  float pos_score = (acc[0] + acc[1]) * (INV_TEMP / (float)B);
  float neg_score = (acc[2] + acc[3]) / (float)B;
  float loss_s = neg_score - pos_score;
  float loss_r = acc[4] / (float)B;
  float reg = LAMBDA2 * acc[5];
  out[0] = loss_r + LAMBDA1 * loss_s + reg;
  out[1] = loss_r;
  out[2] = LAMBDA1 * loss_s;
}

extern "C" void kernel_launch(void* const* d_in, const int* in_sizes, int n_in,
                              void* d_out, int out_size, void* d_ws, size_t ws_size,
                              hipStream_t stream) {
  const float* Eu0  = (const float*)d_in[0];
  const float* Ei0  = (const float*)d_in[1];
  const float* vals = (const float*)d_in[2];
  const float* W    = (const float*)d_in[3];
  const float* al   = (const float*)d_in[4];
  const float* ar   = (const float*)d_in[5];
  const int* ii     = (const int*)d_in[7];
  const int* uids   = (const int*)d_in[10];
  const int* iids   = (const int*)d_in[11];
  const int* pos    = (const int*)d_in[12];
  const int* neg    = (const int*)d_in[13];
  float* out = (float*)d_out;

  char* base = (char*)d_ws;
  size_t off = 0;
  auto alloc = [&](size_t bytes) -> void* {
    void* p = base + off;
    off = (off + bytes + 255) & ~(size_t)255;
    return p;
  };
  float* fU_a = (float*)alloc((size_t)N_U * 128 * 4);
  float* fU_b = (float*)alloc((size_t)N_U * 128 * 4);
  float* fI_a = (float*)alloc((size_t)N_I * 128 * 4);
  float* fI_b = (float*)alloc((size_t)N_I * 128 * 4);
  float* sEu  = (float*)alloc((size_t)N_U * D * 4);
  float* sEi  = (float*)alloc((size_t)N_I * D * 4);
  float* sGu  = (float*)alloc((size_t)N_U * D * 4);
  float* sGi  = (float*)alloc((size_t)N_I * D * 4);
  float* el   = (float*)alloc((size_t)N_TOT * 4 * 4);
  float* er   = (float*)alloc((size_t)N_TOT * 4 * 4);
  float* psU  = (float*)alloc((size_t)B * NSP * 4);
  float* psI  = (float*)alloc((size_t)B * NSP * 4);
  float* M0u  = (float*)alloc((size_t)B * 4);
  float* M0i  = (float*)alloc((size_t)B * 4);
  float* normU= (float*)alloc((size_t)N_U * 4);
  float* normI= (float*)alloc((size_t)N_I * 4);
  float* acc  = (float*)alloc(16 * 4);
  int* deg    = (int*)alloc((size_t)N_I * 4);
  int* cursor = (int*)alloc((size_t)N_I * 4);
  int* rowptr = (int*)alloc((size_t)(N_I + 1) * 4);
  int* u_srt  = (int*)alloc((size_t)NNZ * 4);
  float* v_srt= (float*)alloc((size_t)NNZ * 4);
  unsigned short* EuH = (unsigned short*)alloc((size_t)PAD_U * 64 * 2);
  unsigned short* EuL = (unsigned short*)alloc((size_t)PAD_U * 64 * 2);
  unsigned short* EiH = (unsigned short*)alloc((size_t)PAD_I * 64 * 2);
  unsigned short* EiL = (unsigned short*)alloc((size_t)PAD_I * 64 * 2);
  unsigned short* QuH = (unsigned short*)alloc((size_t)B * 64 * 2);
  unsigned short* QuL = (unsigned short*)alloc((size_t)B * 64 * 2);
  unsigned short* QiH = (unsigned short*)alloc((size_t)B * 64 * 2);
  unsigned short* QiL = (unsigned short*)alloc((size_t)B * 64 * 2);

  k_init<<<(N_TOT * D + 255) / 256, 256, 0, stream>>>(Eu0, Ei0, fU_a, fI_a, sEu, sEi, sGu, sGi,
                                                      deg, acc);
  k_deg<<<(NNZ + 255) / 256, 256, 0, stream>>>(ii, deg);
  k_scan<<<1, 1024, 0, stream>>>(deg, rowptr, cursor);
  k_fill<<<(NNZ + 255) / 256, 256, 0, stream>>>(ii, vals, cursor, u_srt, v_srt);

  float* cu = fU_a; float* ci = fI_a;
  float* nu = fU_b; float* ni = fI_b;
  for (int l = 0; l < 2; ++l) {
    float* elmx = acc + 8 + 4 * l;
    bool last = (l == 1);
    k_feat<<<(N_TOT + 15) / 16, 256, 0, stream>>>(cu, ci, W, al, ar, el, er);
    k_elmax<<<64, 256, 0, stream>>>(el, elmx);
    k_layer<<<(N_TOT * D) / 256, 256, 0, stream>>>(
        cu, ci, el, er, vals, ii, rowptr, u_srt, v_srt, elmx,
        nu, ni, sEu, sEi, sGu, sGi,
        last ? EuH : nullptr, last ? EuL : nullptr,
        last ? EiH : nullptr, last ? EiL : nullptr,
        normU, normI);
    float* t1 = cu; cu = nu; nu = t1;
    float* t2 = ci; ci = ni; ni = t2;
  }

  k_normreg<<<128, 256, 0, stream>>>(normU, normI, Eu0, Ei0, acc);
  k_cvt_q<<<(2 * B) / 4, 256, 0, stream>>>(sGu, sGi, uids, iids, QuH, QuL, QiH, QiL, acc, M0u, M0i);
  k_lse_mfma<<<dim3(B / 512, NSP, 2), 256, 0, stream>>>(QuH, QuL, EuH, EuL,
                                                        QiH, QiL, EiH, EiL,
                                                        M0u, M0i, psU, psI);
  k_small<<<B / 256, 256, 0, stream>>>(sEu, sEi, sGu, sGi, uids, iids, pos, neg,
                                       psU, psI, M0u, M0i, acc);
  k_final<<<1, 1, 0, stream>>>(acc, out);
}

// Round 15
// 422.474 us; speedup vs baseline: 1.1732x; 1.0556x over previous
//
#include <hip/hip_runtime.h>
#include <math.h>

#define N_U 30000
#define N_I 15000
#define N_TOT 45000
#define D 64
#define NNZ 480000
#define B 2048
#define INV_TEMP 5.0f
#define LOG_EPS -18.420680743952367f
#define NEG_SLOPE 0.2f
#define LAMBDA1 0.2f
#define LAMBDA2 1e-7f

// MFMA-lse config
#define NSP 128
#define RSP_U 235
#define RSP_I 118
#define PAD_U 30016
#define PAD_I 15040
#define SCALE_LOG2 7.2134752044448170f
#define LN2F 0.6931471805599453f

typedef __attribute__((ext_vector_type(8))) short short8;
typedef __attribute__((ext_vector_type(4))) float f32x4;

__device__ inline float wred(float v) {
#pragma unroll
  for (int o = 32; o > 0; o >>= 1) v += __shfl_down(v, o, 64);
  return v;
}

__device__ inline float leaky(float v) { return (v >= 0.f) ? v : NEG_SLOPE * v; }

__device__ inline void atomMaxF(float* a, float v) {
  if (v >= 0.f) atomicMax((int*)a, __float_as_int(v));
  else atomicMin((unsigned int*)a, __float_as_uint(v));
}

__device__ inline unsigned short f2bf(float x) {
  unsigned u = __float_as_uint(x);
  unsigned r = u + 0x7FFFu + ((u >> 16) & 1u);
  return (unsigned short)(r >> 16);
}
__device__ inline float bf2f(unsigned short h) {
  return __uint_as_float(((unsigned)h) << 16);
}

// ---------------- init ----------------
__global__ void k_init(const float* __restrict__ Eu0, const float* __restrict__ Ei0,
                       float* fU, float* fI,
                       unsigned short* gU, unsigned short* gI,
                       float* sEu, float* sEi,
                       float* sGu, float* sGi, int* deg, float* acc) {
  int t = blockIdx.x * 256 + threadIdx.x;
  if (t < 16) acc[t] = (t >= 8) ? -INFINITY : 0.f;
  if (t < N_I) deg[t] = 0;
  if (t < N_U * D) {
    int n = t >> 6, c = t & 63;
    float v = Eu0[t];
    fU[(size_t)n * 128 + c] = v;
    gU[(size_t)n * 128 + c] = f2bf(v);
    sEu[t] = v; sGu[t] = v;
  } else if (t < N_TOT * D) {
    int j = t - N_U * D;
    int n = j >> 6, c = j & 63;
    float v = Ei0[j];
    fI[(size_t)n * 128 + c] = v;
    gI[(size_t)n * 128 + c] = f2bf(v);
    sEi[j] = v; sGi[j] = v;
  }
}

// ---------------- CSR build over item side ----------------
__global__ void k_deg(const int* __restrict__ ii, int* deg) {
  int e = blockIdx.x * 256 + threadIdx.x;
  if (e < NNZ) atomicAdd(&deg[ii[e]], 1);
}

__global__ void k_scan(const int* __restrict__ deg, int* rowptr, int* cursor) {
  __shared__ int tsum[1024];
  const int CHUNK = 15;
  int tid = threadIdx.x;
  int base = tid * CHUNK;
  int s = 0;
#pragma unroll
  for (int k = 0; k < CHUNK; k++) {
    int idx = base + k;
    s += (idx < N_I) ? deg[idx] : 0;
  }
  tsum[tid] = s;
  __syncthreads();
  for (int o = 1; o < 1024; o <<= 1) {
    int x = (tid >= o) ? tsum[tid - o] : 0;
    __syncthreads();
    tsum[tid] += x;
    __syncthreads();
  }
  int excl = tsum[tid] - s;
#pragma unroll
  for (int k = 0; k < CHUNK; k++) {
    int idx = base + k;
    if (idx < N_I) {
      rowptr[idx] = excl;
      cursor[idx] = excl;
      excl += deg[idx];
    }
  }
  if (tid == 1023) rowptr[N_I] = tsum[1023];
}

__global__ void k_fill(const int* __restrict__ ii, const float* __restrict__ vals,
                       int* cursor, int* u_srt, float* v_srt) {
  int e = blockIdx.x * 256 + threadIdx.x;
  if (e < NNZ) {
    int pos = atomicAdd(&cursor[ii[e]], 1);
    u_srt[pos] = e >> 4;
    v_srt[pos] = vals[e];
  }
}

// ---------------- GAT: feat = E @ W into fused[64:128] (fp32 + bf16 mirror), el/er ----------------
__global__ void k_feat(float* __restrict__ fU, float* __restrict__ fI,
                       unsigned short* __restrict__ gU, unsigned short* __restrict__ gI,
                       const float* __restrict__ W, const float* __restrict__ al,
                       const float* __restrict__ ar,
                       float* __restrict__ el, float* __restrict__ er) {
  __shared__ float Ws[64 * 64];
  __shared__ float hs[16][64];
  int tid = threadIdx.x;
  for (int t = tid; t < 1024; t += 256) ((float4*)Ws)[t] = ((const float4*)W)[t];
  int g = tid >> 6, c = tid & 63;
  int n0 = blockIdx.x * 16 + g * 4;
  float* rows[4];
  unsigned short* grows[4];
#pragma unroll
  for (int j = 0; j < 4; j++) {
    int node = n0 + j;
    rows[j] = nullptr; grows[j] = nullptr;
    if (node < N_TOT) {
      if (node < N_U) {
        rows[j] = fU + (size_t)node * 128;
        grows[j] = gU + (size_t)node * 128;
      } else {
        rows[j] = fI + (size_t)(node - N_U) * 128;
        grows[j] = gI + (size_t)(node - N_U) * 128;
      }
      hs[g * 4 + j][c] = rows[j][c];
    }
  }
  __syncthreads();
  float a0 = 0.f, a1 = 0.f, a2 = 0.f, a3 = 0.f;
#pragma unroll 8
  for (int k = 0; k < 64; ++k) {
    float w = Ws[k * 64 + c];
    a0 = fmaf(hs[g * 4 + 0][k], w, a0);
    a1 = fmaf(hs[g * 4 + 1][k], w, a1);
    a2 = fmaf(hs[g * 4 + 2][k], w, a2);
    a3 = fmaf(hs[g * 4 + 3][k], w, a3);
  }
  float accs[4] = {a0, a1, a2, a3};
  float alc = al[c], arc = ar[c];
#pragma unroll
  for (int j = 0; j < 4; j++) {
    int node = n0 + j;
    if (node >= N_TOT) continue;
    rows[j][64 + c] = accs[j];
    grows[j][64 + c] = f2bf(accs[j]);
    float pl = accs[j] * alc;
    float pr = accs[j] * arc;
#pragma unroll
    for (int o = 8; o >= 1; o >>= 1) {
      pl += __shfl_down(pl, o, 16);
      pr += __shfl_down(pr, o, 16);
    }
    if ((c & 15) == 0) {
      el[node * 4 + (c >> 4)] = pl;
      er[node * 4 + (c >> 4)] = pr;
    }
  }
}

// ---------------- per-head global max of el ----------------
__global__ void k_elmax(const float* __restrict__ el, float* __restrict__ dst) {
  __shared__ float red[4][4];
  int tid = threadIdx.x;
  int lane = tid & 63, wv = tid >> 6;
  float mx = -INFINITY;
  for (int t = blockIdx.x * 256 + tid; t < N_TOT * 4; t += 64 * 256)
    mx = fmaxf(mx, el[t]);
#pragma unroll
  for (int o = 4; o < 64; o <<= 1) mx = fmaxf(mx, __shfl_xor(mx, o, 64));
  if (lane < 4) red[wv][lane] = mx;
  __syncthreads();
  if (tid < 4) {
    float m2 = fmaxf(fmaxf(red[0][tid], red[1][tid]), fmaxf(red[2][tid], red[3][tid]));
    atomMaxF(dst + tid, m2);
  }
}

// ---------------- fused graph layer: gathers read bf16 mirror; self-reads fp32 ----------------
__global__ void k_layer(const float* __restrict__ fU_cur, const float* __restrict__ fI_cur,
                        const unsigned short* __restrict__ gU_cur,
                        const unsigned short* __restrict__ gI_cur,
                        const float* __restrict__ el, const float* __restrict__ er,
                        const float* __restrict__ vals, const int* __restrict__ ii,
                        const int* __restrict__ rowptr, const int* __restrict__ u_srt,
                        const float* __restrict__ v_srt,
                        const float* __restrict__ elmx,
                        float* __restrict__ fU_nxt, float* __restrict__ fI_nxt,
                        unsigned short* __restrict__ gU_nxt, unsigned short* __restrict__ gI_nxt,
                        float* __restrict__ sEu, float* __restrict__ sEi,
                        float* __restrict__ sGu, float* __restrict__ sGi,
                        unsigned short* __restrict__ EuH, unsigned short* __restrict__ EuL,
                        unsigned short* __restrict__ EiH, unsigned short* __restrict__ EiL,
                        float* __restrict__ normU, float* __restrict__ normI) {
  int t = blockIdx.x * 256 + threadIdx.x;
  int node = t >> 6, c = t & 63;
  if (node >= N_TOT) return;
  int h = c >> 4;

  if (node < N_U) {
    int u = node;
    float eru = er[u * 4 + h];
    float m = leaky(elmx[h] + eru);
    const float* selfrow = fU_cur + (size_t)u * 128;
    float aself = __expf(leaky(el[u * 4 + h] + eru) - m);

    int idx[16]; float vv[16];
#pragma unroll
    for (int k = 0; k < 16; k++) { idx[k] = ii[u * 16 + k]; vv[k] = vals[u * 16 + k]; }
    float av[16];
#pragma unroll
    for (int k = 0; k < 16; k++)
      av[k] = __expf(leaky(el[(idx[k] + N_U) * 4 + h] + eru) - m);

    float den = aself;
#pragma unroll
    for (int k = 0; k < 16; k++) den += av[k];

    float o0 = aself * selfrow[64 + c], o1 = 0.f;
    float z0 = 0.f, z1 = 0.f;
#pragma unroll
    for (int k = 0; k < 16; k += 2) {
      const unsigned short* rA = gI_cur + (size_t)idx[k] * 128;
      const unsigned short* rB = gI_cur + (size_t)idx[k + 1] * 128;
      float eA = bf2f(rA[c]), fA = bf2f(rA[64 + c]);
      float eB = bf2f(rB[c]), fB = bf2f(rB[64 + c]);
      z0 = fmaf(vv[k], eA, z0);
      z1 = fmaf(vv[k + 1], eB, z1);
      o0 = fmaf(av[k], fA, o0);
      o1 = fmaf(av[k + 1], fB, o1);
    }
    float o = (o0 + o1) / den;
    float g = (o > 0.f) ? o : expm1f(o);
    float e_new = selfrow[c] + z0 + z1;
    fU_nxt[(size_t)u * 128 + c] = e_new;
    gU_nxt[(size_t)u * 128 + c] = f2bf(e_new);
    size_t off = (size_t)u * D + c;
    float s_final = sEu[off] + e_new;
    sEu[off] = s_final;
    sGu[off] += g;
    if (EuH) {
      unsigned short hi = f2bf(s_final);
      EuH[off] = hi;
      EuL[off] = f2bf(s_final - bf2f(hi));
      float n2 = wred(s_final * s_final);
      if (c == 0) normU[u] = n2;
    }
  } else {
    int i = node - N_U;
    float eri = er[node * 4 + h];
    float m = leaky(elmx[h] + eri);
    const float* selfrow = fI_cur + (size_t)i * 128;
    float aself = __expf(leaky(el[node * 4 + h] + eri) - m);
    float den0 = aself, den1 = 0.f;
    float o0 = aself * selfrow[64 + c], o1 = 0.f;
    float z0 = 0.f, z1 = 0.f;
    int r0 = rowptr[i], r1 = rowptr[i + 1];
    int r = r0;
    for (; r + 3 < r1; r += 4) {
      int u0 = u_srt[r], u1 = u_srt[r + 1], u2 = u_srt[r + 2], u3 = u_srt[r + 3];
      float v0 = v_srt[r], v1 = v_srt[r + 1], v2 = v_srt[r + 2], v3 = v_srt[r + 3];
      float a0 = __expf(leaky(el[u0 * 4 + h] + eri) - m);
      float a1 = __expf(leaky(el[u1 * 4 + h] + eri) - m);
      float a2 = __expf(leaky(el[u2 * 4 + h] + eri) - m);
      float a3 = __expf(leaky(el[u3 * 4 + h] + eri) - m);
      const unsigned short* R0 = gU_cur + (size_t)u0 * 128;
      const unsigned short* R1 = gU_cur + (size_t)u1 * 128;
      const unsigned short* R2 = gU_cur + (size_t)u2 * 128;
      const unsigned short* R3 = gU_cur + (size_t)u3 * 128;
      float e0 = bf2f(R0[c]), f0 = bf2f(R0[64 + c]);
      float e1 = bf2f(R1[c]), f1 = bf2f(R1[64 + c]);
      float e2 = bf2f(R2[c]), f2 = bf2f(R2[64 + c]);
      float e3 = bf2f(R3[c]), f3 = bf2f(R3[64 + c]);
      z0 = fmaf(v0, e0, z0); z1 = fmaf(v1, e1, z1);
      z0 = fmaf(v2, e2, z0); z1 = fmaf(v3, e3, z1);
      den0 += a0 + a2; den1 += a1 + a3;
      o0 = fmaf(a0, f0, o0); o1 = fmaf(a1, f1, o1);
      o0 = fmaf(a2, f2, o0); o1 = fmaf(a3, f3, o1);
    }
    for (; r < r1; r++) {
      int u0 = u_srt[r];
      float v0 = v_srt[r];
      float a0 = __expf(leaky(el[u0 * 4 + h] + eri) - m);
      const unsigned short* R0 = gU_cur + (size_t)u0 * 128;
      float e0 = bf2f(R0[c]), f0 = bf2f(R0[64 + c]);
      z0 = fmaf(v0, e0, z0);
      den0 += a0;
      o0 = fmaf(a0, f0, o0);
    }
    float o = (o0 + o1) / (den0 + den1);
    float g = (o > 0.f) ? o : expm1f(o);
    float e_new = selfrow[c] + z0 + z1;
    fI_nxt[(size_t)i * 128 + c] = e_new;
    gI_nxt[(size_t)i * 128 + c] = f2bf(e_new);
    size_t off = (size_t)i * D + c;
    float s_final = sEi[off] + e_new;
    sEi[off] = s_final;
    sGi[off] += g;
    if (EiH) {
      unsigned short hi = f2bf(s_final);
      EiH[off] = hi;
      EiL[off] = f2bf(s_final - bf2f(hi));
      float n2 = wred(s_final * s_final);
      if (c == 0) normI[i] = n2;
    }
  }
}

// ---------------- max row-norm reduce + L2 reg reduce (fused) ----------------
__global__ void k_normreg(const float* __restrict__ nU, const float* __restrict__ nI,
                          const float* __restrict__ Eu0, const float* __restrict__ Ei0,
                          float* __restrict__ acc) {
  __shared__ float red[4][3];
  int tid = threadIdx.x;
  int lane = tid & 63, wv = tid >> 6;
  float mu = 0.f, mi = 0.f, s = 0.f;
  for (int t = blockIdx.x * 256 + tid; t < N_U; t += 128 * 256) mu = fmaxf(mu, nU[t]);
  for (int t = blockIdx.x * 256 + tid; t < N_I; t += 128 * 256) mi = fmaxf(mi, nI[t]);
  const float4* A = (const float4*)Eu0;
  const float4* Bp = (const float4*)Ei0;
  const int nA = N_U * 16, nTot = N_TOT * 16;
  for (int t = blockIdx.x * 256 + tid; t < nTot; t += 128 * 256) {
    float4 v = (t < nA) ? A[t] : Bp[t - nA];
    s += v.x * v.x + v.y * v.y + v.z * v.z + v.w * v.w;
  }
#pragma unroll
  for (int o = 32; o > 0; o >>= 1) {
    mu = fmaxf(mu, __shfl_down(mu, o, 64));
    mi = fmaxf(mi, __shfl_down(mi, o, 64));
    s += __shfl_down(s, o, 64);
  }
  if (lane == 0) { red[wv][0] = mu; red[wv][1] = mi; red[wv][2] = s; }
  __syncthreads();
  if (tid == 0) {
    float a = fmaxf(fmaxf(red[0][0], red[1][0]), fmaxf(red[2][0], red[3][0]));
    float b = fmaxf(fmaxf(red[0][1], red[1][1]), fmaxf(red[2][1], red[3][1]));
    float ssum = red[0][2] + red[1][2] + red[2][2] + red[3][2];
    atomMaxF(acc + 6, a);
    atomMaxF(acc + 7, b);
    unsafeAtomicAdd(acc + 5, ssum);
  }
}

// ---------------- gathered queries: pre-scaled split-bf16 + Cauchy-Schwarz offset M0 ----------------
__global__ void k_cvt_q(const float* __restrict__ sGu, const float* __restrict__ sGi,
                        const int* __restrict__ uids, const int* __restrict__ iids,
                        unsigned short* __restrict__ QuH, unsigned short* __restrict__ QuL,
                        unsigned short* __restrict__ QiH, unsigned short* __restrict__ QiL,
                        const float* __restrict__ acc,
                        float* __restrict__ M0u, float* __restrict__ M0i) {
  int lane = threadIdx.x & 63, wv = threadIdx.x >> 6;
  int row = blockIdx.x * 4 + wv;
  int side = row >> 11;
  int b = row & (B - 1);
  int id = side ? iids[b] : uids[b];
  float x = (side ? sGi : sGu)[(size_t)id * 64 + lane] * SCALE_LOG2;
  unsigned short hi = f2bf(x);
  unsigned short lo = f2bf(x - bf2f(hi));
  if (side) { QiH[(size_t)b * 64 + lane] = hi; QiL[(size_t)b * 64 + lane] = lo; }
  else      { QuH[(size_t)b * 64 + lane] = hi; QuL[(size_t)b * 64 + lane] = lo; }
  float n2 = wred(x * x);
  if (lane == 0) {
    float en2 = side ? acc[7] : acc[6];
    float M0 = sqrtf(n2) * sqrtf(en2) * 1.01f + 1.0f;
    (side ? M0i : M0u)[b] = M0;
  }
}

// ---------------- MFMA logsumexp: both sides in one dispatch (blockIdx.z) ----------------
__global__ __launch_bounds__(256, 2) void k_lse_mfma(
    const unsigned short* __restrict__ QuH, const unsigned short* __restrict__ QuL,
    const unsigned short* __restrict__ EuHp, const unsigned short* __restrict__ EuLp,
    const unsigned short* __restrict__ QiH, const unsigned short* __restrict__ QiL,
    const unsigned short* __restrict__ EiHp, const unsigned short* __restrict__ EiLp,
    const float* __restrict__ M0u, const float* __restrict__ M0i,
    float* __restrict__ psU, float* __restrict__ psI) {
  int z = blockIdx.z;
  const unsigned short* Qhi = z ? QiH : QuH;
  const unsigned short* Qlo = z ? QiL : QuL;
  const unsigned short* Ehi = z ? EiHp : EuHp;
  const unsigned short* Elo = z ? EiLp : EuLp;
  const float* M0arr = z ? M0i : M0u;
  float* part_s = z ? psI : psU;
  int n_rows = z ? N_I : N_U;
  int rows_per_split = z ? RSP_I : RSP_U;

  int tid = threadIdx.x;
  int wave = tid >> 6, lane = tid & 63;
  int l15 = lane & 15, quad = lane >> 4;
  int qbase = (blockIdx.x * 4 + wave) * 128;
  int split = blockIdx.y;
  int row0 = split * rows_per_split;
  int row_end = min(row0 + rows_per_split, n_rows);
  int rows = row_end - row0; if (rows < 0) rows = 0;
  int total = (rows + 15) >> 4;
  int ntail = rows & 15;

  float ss[8][4];
#pragma unroll
  for (int t = 0; t < 8; t++)
#pragma unroll
    for (int g = 0; g < 4; g++) ss[t][g] = 0.f;

  if (total > 0) {
    short8 ah[8][2], al[8][2];
#pragma unroll
    for (int t = 0; t < 8; t++)
#pragma unroll
      for (int c = 0; c < 2; c++) {
        size_t idx = (size_t)(qbase + t * 16 + l15) * 64 + c * 32 + quad * 8;
        ah[t][c] = *(const short8*)(Qhi + idx);
        al[t][c] = *(const short8*)(Qlo + idx);
      }

    f32x4 cinit[8];
#pragma unroll
    for (int t = 0; t < 8; t++)
#pragma unroll
      for (int g = 0; g < 4; g++)
        cinit[t][g] = -M0arr[qbase + t * 16 + quad * 4 + g];

    const unsigned short* ph = Ehi + (size_t)(row0 + l15) * 64 + quad * 8;
    const unsigned short* pl = Elo + (size_t)(row0 + l15) * 64 + quad * 8;

    short8 cb0 = *(const short8*)(ph);
    short8 cb1 = *(const short8*)(ph + 32);
    short8 cb2 = *(const short8*)(pl);
    short8 cb3 = *(const short8*)(pl + 32);
    ph += 1024; pl += 1024;

    for (int it = 0; it < total - 1; it++) {
      short8 nb0 = *(const short8*)(ph);
      short8 nb1 = *(const short8*)(ph + 32);
      short8 nb2 = *(const short8*)(pl);
      short8 nb3 = *(const short8*)(pl + 32);
      ph += 1024; pl += 1024;
#pragma unroll
      for (int t = 0; t < 8; t++) {
        f32x4 acc = cinit[t];
        acc = __builtin_amdgcn_mfma_f32_16x16x32_bf16(ah[t][0], cb0, acc, 0, 0, 0);
        acc = __builtin_amdgcn_mfma_f32_16x16x32_bf16(ah[t][1], cb1, acc, 0, 0, 0);
        acc = __builtin_amdgcn_mfma_f32_16x16x32_bf16(al[t][0], cb0, acc, 0, 0, 0);
        acc = __builtin_amdgcn_mfma_f32_16x16x32_bf16(al[t][1], cb1, acc, 0, 0, 0);
        acc = __builtin_amdgcn_mfma_f32_16x16x32_bf16(ah[t][0], cb2, acc, 0, 0, 0);
        acc = __builtin_amdgcn_mfma_f32_16x16x32_bf16(ah[t][1], cb3, acc, 0, 0, 0);
#pragma unroll
        for (int g = 0; g < 4; g++)
          ss[t][g] += exp2f(acc[g]);
      }
      cb0 = nb0; cb1 = nb1; cb2 = nb2; cb3 = nb3;
    }
    {
      bool valid = (ntail == 0) || (l15 < ntail);
#pragma unroll
      for (int t = 0; t < 8; t++) {
        f32x4 acc = cinit[t];
        acc = __builtin_amdgcn_mfma_f32_16x16x32_bf16(ah[t][0], cb0, acc, 0, 0, 0);
        acc = __builtin_amdgcn_mfma_f32_16x16x32_bf16(ah[t][1], cb1, acc, 0, 0, 0);
        acc = __builtin_amdgcn_mfma_f32_16x16x32_bf16(al[t][0], cb0, acc, 0, 0, 0);
        acc = __builtin_amdgcn_mfma_f32_16x16x32_bf16(al[t][1], cb1, acc, 0, 0, 0);
        acc = __builtin_amdgcn_mfma_f32_16x16x32_bf16(ah[t][0], cb2, acc, 0, 0, 0);
        acc = __builtin_amdgcn_mfma_f32_16x16x32_bf16(ah[t][1], cb3, acc, 0, 0, 0);
#pragma unroll
        for (int g = 0; g < 4; g++) {
          float e = exp2f(acc[g]);
          ss[t][g] += valid ? e : 0.f;
        }
      }
    }
  }

#pragma unroll
  for (int off = 1; off < 16; off <<= 1) {
#pragma unroll
    for (int t = 0; t < 8; t++)
#pragma unroll
      for (int g = 0; g < 4; g++)
        ss[t][g] += __shfl_xor(ss[t][g], off, 64);
  }

  if (l15 == 0) {
#pragma unroll
    for (int t = 0; t < 8; t++)
#pragma unroll
      for (int g = 0; g < 4; g++) {
        int q = qbase + t * 16 + quad * 4 + g;
        part_s[(size_t)split * B + q] = ss[t][g];
      }
  }
}

// ---------------- per-sample losses ----------------
__global__ void k_small(const float* __restrict__ sEu, const float* __restrict__ sEi,
                        const float* __restrict__ sGu, const float* __restrict__ sGi,
                        const int* __restrict__ uids, const int* __restrict__ iids,
                        const int* __restrict__ pos, const int* __restrict__ neg,
                        const float* __restrict__ psU, const float* __restrict__ psI,
                        const float* __restrict__ M0u, const float* __restrict__ M0i,
                        float* acc) {
  int b = blockIdx.x * 256 + threadIdx.x;
  float du = 0.f, di = 0.f, nu = 0.f, ni = 0.f, bpr = 0.f;
  if (b < B) {
    float su = 0.f, si = 0.f;
    for (int s2 = 0; s2 < NSP; s2++) su += psU[(size_t)s2 * B + b];
    for (int s2 = 0; s2 < NSP; s2++) si += psI[(size_t)s2 * B + b];
    float lseu = M0u[b] * LN2F + logf(su);
    float lsei = M0i[b] * LN2F + logf(si);
    nu = fmaxf(lseu, LOG_EPS) + log1pf(expf(-fabsf(lseu - LOG_EPS)));
    ni = fmaxf(lsei, LOG_EPS) + log1pf(expf(-fabsf(lsei - LOG_EPS)));

    int u = uids[b], it = iids[b], p = pos[b], ng = neg[b];
    const float4* gu = (const float4*)(sGu + (size_t)u * D);
    const float4* eu = (const float4*)(sEu + (size_t)u * D);
    const float4* gi = (const float4*)(sGi + (size_t)it * D);
    const float4* ei = (const float4*)(sEi + (size_t)it * D);
    const float4* ep = (const float4*)(sEi + (size_t)p * D);
    const float4* en = (const float4*)(sEi + (size_t)ng * D);
    float diff = 0.f;
#pragma unroll
    for (int k = 0; k < 16; k++) {
      float4 a = gu[k], b4 = eu[k];
      du += a.x * b4.x + a.y * b4.y + a.z * b4.z + a.w * b4.w;
      float4 c = gi[k], d4 = ei[k];
      di += c.x * d4.x + c.y * d4.y + c.z * d4.z + c.w * d4.w;
      float4 e = ep[k], f = en[k];
      diff += b4.x * (e.x - f.x) + b4.y * (e.y - f.y) + b4.z * (e.z - f.z) + b4.w * (e.w - f.w);
    }
    bpr = (diff > 0.f) ? log1pf(expf(-diff)) : (-diff + log1pf(expf(diff)));
  }
  du = wred(du); di = wred(di); nu = wred(nu); ni = wred(ni); bpr = wred(bpr);
  if ((threadIdx.x & 63) == 0) {
    unsafeAtomicAdd(acc + 0, du);
    unsafeAtomicAdd(acc + 1, di);
    unsafeAtomicAdd(acc + 2, nu);
    unsafeAtomicAdd(acc + 3, ni);
    unsafeAtomicAdd(acc + 4, bpr);
  }
}

// ---------------- finalize ----------------
__global__ void k_final(const float* __restrict__ acc, float* __restrict__ out) {
  float pos_score = (acc[0] + acc[1]) * (INV_TEMP / (float)B);
  float neg_score = (acc[2] + acc[3]) / (float)B;
  float loss_s = neg_score - pos_score;
  float loss_r = acc[4] / (float)B;
  float reg = LAMBDA2 * acc[5];
  out[0] = loss_r + LAMBDA1 * loss_s + reg;
  out[1] = loss_r;
  out[2] = LAMBDA1 * loss_s;
}

extern "C" void kernel_launch(void* const* d_in, const int* in_sizes, int n_in,
                              void* d_out, int out_size, void* d_ws, size_t ws_size,
                              hipStream_t stream) {
  const float* Eu0  = (const float*)d_in[0];
  const float* Ei0  = (const float*)d_in[1];
  const float* vals = (const float*)d_in[2];
  const float* W    = (const float*)d_in[3];
  const float* al   = (const float*)d_in[4];
  const float* ar   = (const float*)d_in[5];
  const int* ii     = (const int*)d_in[7];
  const int* uids   = (const int*)d_in[10];
  const int* iids   = (const int*)d_in[11];
  const int* pos    = (const int*)d_in[12];
  const int* neg    = (const int*)d_in[13];
  float* out = (float*)d_out;

  char* base = (char*)d_ws;
  size_t off = 0;
  auto alloc = [&](size_t bytes) -> void* {
    void* p = base + off;
    off = (off + bytes + 255) & ~(size_t)255;
    return p;
  };
  float* fU_a = (float*)alloc((size_t)N_U * 128 * 4);
  float* fU_b = (float*)alloc((size_t)N_U * 128 * 4);
  float* fI_a = (float*)alloc((size_t)N_I * 128 * 4);
  float* fI_b = (float*)alloc((size_t)N_I * 128 * 4);
  unsigned short* gU_a = (unsigned short*)alloc((size_t)N_U * 128 * 2);
  unsigned short* gU_b = (unsigned short*)alloc((size_t)N_U * 128 * 2);
  unsigned short* gI_a = (unsigned short*)alloc((size_t)N_I * 128 * 2);
  unsigned short* gI_b = (unsigned short*)alloc((size_t)N_I * 128 * 2);
  float* sEu  = (float*)alloc((size_t)N_U * D * 4);
  float* sEi  = (float*)alloc((size_t)N_I * D * 4);
  float* sGu  = (float*)alloc((size_t)N_U * D * 4);
  float* sGi  = (float*)alloc((size_t)N_I * D * 4);
  float* el   = (float*)alloc((size_t)N_TOT * 4 * 4);
  float* er   = (float*)alloc((size_t)N_TOT * 4 * 4);
  float* psU  = (float*)alloc((size_t)B * NSP * 4);
  float* psI  = (float*)alloc((size_t)B * NSP * 4);
  float* M0u  = (float*)alloc((size_t)B * 4);
  float* M0i  = (float*)alloc((size_t)B * 4);
  float* normU= (float*)alloc((size_t)N_U * 4);
  float* normI= (float*)alloc((size_t)N_I * 4);
  float* acc  = (float*)alloc(16 * 4);
  int* deg    = (int*)alloc((size_t)N_I * 4);
  int* cursor = (int*)alloc((size_t)N_I * 4);
  int* rowptr = (int*)alloc((size_t)(N_I + 1) * 4);
  int* u_srt  = (int*)alloc((size_t)NNZ * 4);
  float* v_srt= (float*)alloc((size_t)NNZ * 4);
  unsigned short* EuH = (unsigned short*)alloc((size_t)PAD_U * 64 * 2);
  unsigned short* EuL = (unsigned short*)alloc((size_t)PAD_U * 64 * 2);
  unsigned short* EiH = (unsigned short*)alloc((size_t)PAD_I * 64 * 2);
  unsigned short* EiL = (unsigned short*)alloc((size_t)PAD_I * 64 * 2);
  unsigned short* QuH = (unsigned short*)alloc((size_t)B * 64 * 2);
  unsigned short* QuL = (unsigned short*)alloc((size_t)B * 64 * 2);
  unsigned short* QiH = (unsigned short*)alloc((size_t)B * 64 * 2);
  unsigned short* QiL = (unsigned short*)alloc((size_t)B * 64 * 2);

  k_init<<<(N_TOT * D + 255) / 256, 256, 0, stream>>>(Eu0, Ei0, fU_a, fI_a, gU_a, gI_a,
                                                      sEu, sEi, sGu, sGi, deg, acc);
  k_deg<<<(NNZ + 255) / 256, 256, 0, stream>>>(ii, deg);
  k_scan<<<1, 1024, 0, stream>>>(deg, rowptr, cursor);
  k_fill<<<(NNZ + 255) / 256, 256, 0, stream>>>(ii, vals, cursor, u_srt, v_srt);

  float* cu = fU_a; float* ci = fI_a;
  float* nu = fU_b; float* ni = fI_b;
  unsigned short* gcu = gU_a; unsigned short* gci = gI_a;
  unsigned short* gnu = gU_b; unsigned short* gni = gI_b;
  for (int l = 0; l < 2; ++l) {
    float* elmx = acc + 8 + 4 * l;
    bool last = (l == 1);
    k_feat<<<(N_TOT + 15) / 16, 256, 0, stream>>>(cu, ci, gcu, gci, W, al, ar, el, er);
    k_elmax<<<64, 256, 0, stream>>>(el, elmx);
    k_layer<<<(N_TOT * D) / 256, 256, 0, stream>>>(
        cu, ci, gcu, gci, el, er, vals, ii, rowptr, u_srt, v_srt, elmx,
        nu, ni, gnu, gni, sEu, sEi, sGu, sGi,
        last ? EuH : nullptr, last ? EuL : nullptr,
        last ? EiH : nullptr, last ? EiL : nullptr,
        normU, normI);
    float* t1 = cu; cu = nu; nu = t1;
    float* t2 = ci; ci = ni; ni = t2;
    unsigned short* t3 = gcu; gcu = gnu; gnu = t3;
    unsigned short* t4 = gci; gci = gni; gni = t4;
  }

  k_normreg<<<128, 256, 0, stream>>>(normU, normI, Eu0, Ei0, acc);
  k_cvt_q<<<(2 * B) / 4, 256, 0, stream>>>(sGu, sGi, uids, iids, QuH, QuL, QiH, QiL, acc, M0u, M0i);
  k_lse_mfma<<<dim3(B / 512, NSP, 2), 256, 0, stream>>>(QuH, QuL, EuH, EuL,
                                                        QiH, QiL, EiH, EiL,
                                                        M0u, M0i, psU, psI);
  k_small<<<B / 256, 256, 0, stream>>>(sEu, sEi, sGu, sGi, uids, iids, pos, neg,
                                       psU, psI, M0u, M0i, acc);
  k_final<<<1, 1, 0, stream>>>(acc, out);
}